// Round 1
// baseline (1677.262 us; speedup 1.0000x reference)
//
#include <hip/hip_runtime.h>
#include <hip/hip_bf16.h>
#include <math.h>

#define NODES 20000
#define EDGES 320000
#define NB 3
#define TOTN (NODES * NB)   // 60000
#define TOTE (EDGES * NB)   // 960000
#define D_IN 128
#define D_H 304

// ---------------- pack x1|x2|x3 -> Q (60000 x 128) ----------------
__global__ void k_pack(const float4* __restrict__ x1, const float4* __restrict__ x2,
                       const float4* __restrict__ x3, float4* __restrict__ q) {
    const int per = NODES * D_IN / 4;  // 640000
    int i = blockIdx.x * 256 + threadIdx.x;
    if (i >= 3 * per) return;
    const float4* s; int j;
    if (i < per)            { s = x1; j = i; }
    else if (i < 2 * per)   { s = x2; j = i - per; }
    else                    { s = x3; j = i - 2 * per; }
    q[i] = s[j];
}

// ---------------- degree counting ----------------
__global__ void k_deg(const int* __restrict__ s1, const int* __restrict__ d1,
                      const int* __restrict__ s2, const int* __restrict__ d2,
                      const int* __restrict__ s3, const int* __restrict__ d3,
                      int* __restrict__ out_cnt, int* __restrict__ in_cnt) {
    int e = blockIdx.x * 256 + threadIdx.x;
    if (e >= TOTE) return;
    int g = e / EDGES;
    int le = e - g * EDGES;
    const int* sp = (g == 0) ? s1 : ((g == 1) ? s2 : s3);
    const int* dp = (g == 0) ? d1 : ((g == 1) ? d2 : d3);
    int s = sp[le] + g * NODES;
    int d = dp[le] + g * NODES;
    atomicAdd(&out_cnt[s], 1);
    atomicAdd(&in_cnt[d], 1);
}

__global__ void k_inv(const int* __restrict__ out_cnt, const int* __restrict__ in_cnt,
                      float* __restrict__ inv_out, float* __restrict__ inv_in) {
    int n = blockIdx.x * 256 + threadIdx.x;
    if (n >= TOTN) return;
    inv_out[n] = 1.0f / sqrtf((float)max(out_cnt[n], 1));
    inv_in[n]  = 1.0f / sqrtf((float)max(in_cnt[n], 1));
}

// ---------------- single-block scan over in_cnt -> row_ptr, cursor ----------------
__global__ void k_scan(const int* __restrict__ cnt, int* __restrict__ row_ptr,
                       int* __restrict__ cursor) {
    __shared__ int wsum[16];
    int t = threadIdx.x;          // 1024 threads = 16 waves
    int lane = t & 63, wid = t >> 6;
    int base = 0;
    for (int start = 0; start < TOTN; start += 1024) {
        int i = start + t;
        int v = (i < TOTN) ? cnt[i] : 0;
        int sv = v;
        #pragma unroll
        for (int o = 1; o < 64; o <<= 1) {
            int u = __shfl_up(sv, o, 64);
            if (lane >= o) sv += u;
        }
        if (lane == 63) wsum[wid] = sv;
        __syncthreads();
        if (t < 16) {
            int w = wsum[t];
            #pragma unroll
            for (int o = 1; o < 16; o <<= 1) {
                int u = __shfl_up(w, o, 16);
                if (t >= o) w += u;
            }
            wsum[t] = w;
        }
        __syncthreads();
        int wbase = (wid > 0) ? wsum[wid - 1] : 0;
        int excl = base + wbase + sv - v;
        if (i < TOTN) { row_ptr[i] = excl; cursor[i] = excl; }
        int tot = wsum[15];
        __syncthreads();
        base += tot;
    }
    if (t == 0) row_ptr[TOTN] = base;
}

// ---------------- CSR fill (incoming edges grouped by dst) ----------------
__global__ void k_fill(const int* __restrict__ s1, const int* __restrict__ d1,
                       const int* __restrict__ s2, const int* __restrict__ d2,
                       const int* __restrict__ s3, const int* __restrict__ d3,
                       int* __restrict__ cursor, int* __restrict__ csr) {
    int e = blockIdx.x * 256 + threadIdx.x;
    if (e >= TOTE) return;
    int g = e / EDGES;
    int le = e - g * EDGES;
    const int* sp = (g == 0) ? s1 : ((g == 1) ? s2 : s3);
    const int* dp = (g == 0) ? d1 : ((g == 1) ? d2 : d3);
    int s = sp[le] + g * NODES;
    int d = dp[le] + g * NODES;
    int pos = atomicAdd(&cursor[d], 1);
    csr[pos] = s;
}

// ---------------- SpMM gather: agg[n] = inv_in[n] * sum_e h[src]*inv_out[src] ----------------
template <int D>
__global__ void k_spmm(const float* __restrict__ h, float* __restrict__ agg,
                       const int* __restrict__ row_ptr, const int* __restrict__ csr,
                       const float* __restrict__ inv_out, const float* __restrict__ inv_in) {
    constexpr int NC = (D + 127) / 128;  // 1 for D=128, 3 for D=304
    int n = blockIdx.x;
    int t = threadIdx.x;  // 128 threads
    float acc[NC];
    #pragma unroll
    for (int c = 0; c < NC; c++) acc[c] = 0.f;
    int k0 = row_ptr[n], k1 = row_ptr[n + 1];
    for (int k = k0; k < k1; k++) {
        int s = csr[k];
        float w = inv_out[s];
        const float* hr = h + (size_t)s * D;
        #pragma unroll
        for (int c = 0; c < NC; c++) {
            int col = t + c * 128;
            if (col < D) acc[c] += hr[col] * w;
        }
    }
    float wi = inv_in[n];
    float* ar = agg + (size_t)n * D;
    #pragma unroll
    for (int c = 0; c < NC; c++) {
        int col = t + c * 128;
        if (col < D) ar[col] = acc[c] * wi;
    }
}

// ---------------- fp32 tiled GEMM: C = relu(A[MxK] @ W[Kx304] + bias) ----------------
__global__ __launch_bounds__(256) void k_gemm(const float* __restrict__ A,
                                              const float* __restrict__ W,
                                              const float* __restrict__ bias,
                                              float* __restrict__ C, int M, int K) {
    __shared__ float As[16][65];  // [k][m], padded
    __shared__ float Bs[16][65];  // [k][n]
    int tid = threadIdx.x;
    int tm = tid >> 4, tn = tid & 15;
    int bm = blockIdx.x * 64;
    int bn = blockIdx.y * 64;
    float c[4][4] = {};
    for (int kt = 0; kt < K; kt += 16) {
        #pragma unroll
        for (int j = 0; j < 4; j++) {
            int idx = j * 256 + tid;        // 0..1023
            int m = idx >> 4, k = idx & 15;
            int row = bm + m;
            float v = 0.f;
            if (row < M) v = A[(size_t)row * K + kt + k];
            As[k][m] = v;
        }
        #pragma unroll
        for (int j = 0; j < 4; j++) {
            int idx = j * 256 + tid;
            int k = idx >> 6, n = idx & 63;
            int col = bn + n;
            float v = 0.f;
            if (col < D_H) v = W[(size_t)(kt + k) * D_H + col];
            Bs[k][n] = v;
        }
        __syncthreads();
        #pragma unroll
        for (int kk = 0; kk < 16; kk++) {
            float a[4], b[4];
            #pragma unroll
            for (int i = 0; i < 4; i++) a[i] = As[kk][tm * 4 + i];
            #pragma unroll
            for (int j = 0; j < 4; j++) b[j] = Bs[kk][tn * 4 + j];
            #pragma unroll
            for (int i = 0; i < 4; i++)
                #pragma unroll
                for (int j = 0; j < 4; j++) c[i][j] += a[i] * b[j];
        }
        __syncthreads();
    }
    #pragma unroll
    for (int i = 0; i < 4; i++) {
        int row = bm + tm * 4 + i;
        if (row >= M) continue;
        #pragma unroll
        for (int j = 0; j < 4; j++) {
            int col = bn + tn * 4 + j;
            if (col < D_H) {
                float v = c[i][j] + bias[col];
                C[(size_t)row * D_H + col] = fmaxf(v, 0.f);
            }
        }
    }
}

// ---------------- column max-pool over all 60000 rows ----------------
__global__ void k_pool(const float* __restrict__ h, int* __restrict__ pooled) {
    int c = threadIdx.x;   // 320 threads, 304 active
    if (c >= D_H) return;
    int r0 = blockIdx.x * 256;
    int r1 = min(r0 + 256, TOTN);
    float m = 0.f;  // relu outputs are >= 0
    for (int r = r0; r < r1; r++) m = fmaxf(m, h[(size_t)r * D_H + c]);
    atomicMax(&pooled[c], __float_as_int(m));  // valid: all values >= 0
}

// ---------------- MLP head: 304 -> 128 -> 64 -> 1, sigmoid ----------------
__global__ void k_mlp(const int* __restrict__ pooled_i,
                      const float* __restrict__ fW1, const float* __restrict__ fb1,
                      const float* __restrict__ fW2, const float* __restrict__ fb2,
                      const float* __restrict__ fW3, const float* __restrict__ fb3,
                      float* __restrict__ out) {
    __shared__ float p[D_H];
    __shared__ float z1[128];
    __shared__ float z2[64];
    int t = threadIdx.x;  // 320
    if (t < D_H) p[t] = __int_as_float(pooled_i[t]);
    __syncthreads();
    if (t < 128) {
        float acc = fb1[t];
        for (int k = 0; k < D_H; k++) acc += p[k] * fW1[k * 128 + t];
        z1[t] = fmaxf(acc, 0.f);
    }
    __syncthreads();
    if (t < 64) {
        float acc = fb2[t];
        for (int k = 0; k < 128; k++) acc += z1[k] * fW2[k * 64 + t];
        z2[t] = fmaxf(acc, 0.f);
    }
    __syncthreads();
    if (t == 0) {
        float acc = fb3[0];
        for (int k = 0; k < 64; k++) acc += z2[k] * fW3[k];
        out[0] = 1.f / (1.f + expf(-acc));
    }
}

extern "C" void kernel_launch(void* const* d_in, const int* in_sizes, int n_in,
                              void* d_out, int out_size, void* d_ws, size_t ws_size,
                              hipStream_t stream) {
    const float* x1 = (const float*)d_in[0];
    const float* x2 = (const float*)d_in[1];
    const float* x3 = (const float*)d_in[2];
    const int* src1 = (const int*)d_in[3];
    const int* dst1 = (const int*)d_in[4];
    const int* src2 = (const int*)d_in[5];
    const int* dst2 = (const int*)d_in[6];
    const int* src3 = (const int*)d_in[7];
    const int* dst3 = (const int*)d_in[8];
    const float* W1 = (const float*)d_in[9];
    const float* b1 = (const float*)d_in[10];
    const float* W2 = (const float*)d_in[11];
    const float* b2 = (const float*)d_in[12];
    const float* W3 = (const float*)d_in[13];
    const float* b3 = (const float*)d_in[14];
    const float* fW1 = (const float*)d_in[15];
    const float* fb1 = (const float*)d_in[16];
    const float* fW2 = (const float*)d_in[17];
    const float* fb2 = (const float*)d_in[18];
    const float* fW3 = (const float*)d_in[19];
    const float* fb3 = (const float*)d_in[20];
    float* out = (float*)d_out;

    char* w = (char*)d_ws;
    float* P       = (float*)w; w += (size_t)TOTN * D_H * 4;
    float* Q       = (float*)w; w += (size_t)TOTN * D_H * 4;
    float* inv_out = (float*)w; w += (size_t)TOTN * 4;
    float* inv_in  = (float*)w; w += (size_t)TOTN * 4;
    int* out_cnt   = (int*)w;   w += (size_t)TOTN * 4;
    int* in_cnt    = (int*)w;   w += (size_t)TOTN * 4;
    int* row_ptr   = (int*)w;   w += (size_t)(TOTN + 1) * 4;
    int* cursor    = (int*)w;   w += (size_t)TOTN * 4;
    int* csr       = (int*)w;   w += (size_t)TOTE * 4;
    int* pooled    = (int*)w;   w += (size_t)D_H * 4;

    hipMemsetAsync(out_cnt, 0, 2 * (size_t)TOTN * 4, stream);  // out_cnt + in_cnt contiguous
    hipMemsetAsync(pooled, 0, D_H * 4, stream);

    k_pack<<<(3 * NODES * D_IN / 4 + 255) / 256, 256, 0, stream>>>(
        (const float4*)x1, (const float4*)x2, (const float4*)x3, (float4*)Q);
    k_deg<<<(TOTE + 255) / 256, 256, 0, stream>>>(src1, dst1, src2, dst2, src3, dst3,
                                                  out_cnt, in_cnt);
    k_inv<<<(TOTN + 255) / 256, 256, 0, stream>>>(out_cnt, in_cnt, inv_out, inv_in);
    k_scan<<<1, 1024, 0, stream>>>(in_cnt, row_ptr, cursor);
    k_fill<<<(TOTE + 255) / 256, 256, 0, stream>>>(src1, dst1, src2, dst2, src3, dst3,
                                                   cursor, csr);

    dim3 ggrid((TOTN + 63) / 64, (D_H + 63) / 64);

    // layer 1: x(128) -> SpMM -> GEMM(K=128) -> Q(304)
    k_spmm<128><<<TOTN, 128, 0, stream>>>(Q, P, row_ptr, csr, inv_out, inv_in);
    k_gemm<<<ggrid, 256, 0, stream>>>(P, W1, b1, Q, TOTN, 128);
    // layer 2
    k_spmm<304><<<TOTN, 128, 0, stream>>>(Q, P, row_ptr, csr, inv_out, inv_in);
    k_gemm<<<ggrid, 256, 0, stream>>>(P, W2, b2, Q, TOTN, 304);
    // layer 3
    k_spmm<304><<<TOTN, 128, 0, stream>>>(Q, P, row_ptr, csr, inv_out, inv_in);
    k_gemm<<<ggrid, 256, 0, stream>>>(P, W3, b3, Q, TOTN, 304);

    k_pool<<<(TOTN + 255) / 256, 320, 0, stream>>>(Q, pooled);
    k_mlp<<<1, 320, 0, stream>>>(pooled, fW1, fb1, fW2, fb2, fW3, fb3, out);
}

// Round 2
// 908.906 us; speedup vs baseline: 1.8454x; 1.8454x over previous
//
#include <hip/hip_runtime.h>
#include <hip/hip_bf16.h>
#include <math.h>

#define NODES 20000
#define EDGES 320000
#define NB 3
#define TOTN (NODES * NB)   // 60000
#define TOTE (EDGES * NB)   // 960000
#define D_IN 128
#define D_H 304
#define LDT 40              // LDS row stride (shorts) — breaks pow2 bank pattern

typedef __attribute__((ext_vector_type(8))) short short8;
typedef __attribute__((ext_vector_type(4))) float f32x4;

__device__ __forceinline__ unsigned short f2bf(float f) {
    unsigned u = __float_as_uint(f);
    unsigned r = (u + 0x7fffu + ((u >> 16) & 1u)) >> 16;   // RNE
    return (unsigned short)r;
}
__device__ __forceinline__ float bf_lo(unsigned u) { return __uint_as_float(u << 16); }
__device__ __forceinline__ float bf_hi(unsigned u) { return __uint_as_float(u & 0xffff0000u); }

// ---------------- pack x1|x2|x3 fp32 -> X bf16 (60000 x 128) ----------------
__global__ void k_pack(const float2* __restrict__ x1, const float2* __restrict__ x2,
                       const float2* __restrict__ x3, unsigned* __restrict__ q) {
    const int per = NODES * D_IN / 2;  // dwords-out per graph
    int i = blockIdx.x * 256 + threadIdx.x;
    if (i >= 3 * per) return;
    const float2* s; int j;
    if (i < per)          { s = x1; j = i; }
    else if (i < 2 * per) { s = x2; j = i - per; }
    else                  { s = x3; j = i - 2 * per; }
    float2 v = s[j];
    q[i] = (unsigned)f2bf(v.x) | ((unsigned)f2bf(v.y) << 16);
}

// ---------------- degree counting ----------------
__global__ void k_deg(const int* __restrict__ s1, const int* __restrict__ d1,
                      const int* __restrict__ s2, const int* __restrict__ d2,
                      const int* __restrict__ s3, const int* __restrict__ d3,
                      int* __restrict__ out_cnt, int* __restrict__ in_cnt) {
    int e = blockIdx.x * 256 + threadIdx.x;
    if (e >= TOTE) return;
    int g = e / EDGES;
    int le = e - g * EDGES;
    const int* sp = (g == 0) ? s1 : ((g == 1) ? s2 : s3);
    const int* dp = (g == 0) ? d1 : ((g == 1) ? d2 : d3);
    int s = sp[le] + g * NODES;
    int d = dp[le] + g * NODES;
    atomicAdd(&out_cnt[s], 1);
    atomicAdd(&in_cnt[d], 1);
}

__global__ void k_inv(const int* __restrict__ out_cnt, const int* __restrict__ in_cnt,
                      float* __restrict__ inv_out, float* __restrict__ inv_in) {
    int n = blockIdx.x * 256 + threadIdx.x;
    if (n >= TOTN) return;
    inv_out[n] = 1.0f / sqrtf((float)max(out_cnt[n], 1));
    inv_in[n]  = 1.0f / sqrtf((float)max(in_cnt[n], 1));
}

// ---------------- single-block scan over in_cnt -> row_ptr, cursor ----------------
__global__ void k_scan(const int* __restrict__ cnt, int* __restrict__ row_ptr,
                       int* __restrict__ cursor) {
    __shared__ int wsum[16];
    int t = threadIdx.x;          // 1024 threads = 16 waves
    int lane = t & 63, wid = t >> 6;
    int base = 0;
    for (int start = 0; start < TOTN; start += 1024) {
        int i = start + t;
        int v = (i < TOTN) ? cnt[i] : 0;
        int sv = v;
        #pragma unroll
        for (int o = 1; o < 64; o <<= 1) {
            int u = __shfl_up(sv, o, 64);
            if (lane >= o) sv += u;
        }
        if (lane == 63) wsum[wid] = sv;
        __syncthreads();
        if (t < 16) {
            int w = wsum[t];
            #pragma unroll
            for (int o = 1; o < 16; o <<= 1) {
                int u = __shfl_up(w, o, 16);
                if (t >= o) w += u;
            }
            wsum[t] = w;
        }
        __syncthreads();
        int wbase = (wid > 0) ? wsum[wid - 1] : 0;
        int excl = base + wbase + sv - v;
        if (i < TOTN) { row_ptr[i] = excl; cursor[i] = excl; }
        int tot = wsum[15];
        __syncthreads();
        base += tot;
    }
    if (t == 0) row_ptr[TOTN] = base;
}

// ---------------- CSR fill (incoming edges grouped by dst) ----------------
__global__ void k_fill(const int* __restrict__ s1, const int* __restrict__ d1,
                       const int* __restrict__ s2, const int* __restrict__ d2,
                       const int* __restrict__ s3, const int* __restrict__ d3,
                       int* __restrict__ cursor, int* __restrict__ csr) {
    int e = blockIdx.x * 256 + threadIdx.x;
    if (e >= TOTE) return;
    int g = e / EDGES;
    int le = e - g * EDGES;
    const int* sp = (g == 0) ? s1 : ((g == 1) ? s2 : s3);
    const int* dp = (g == 0) ? d1 : ((g == 1) ? d2 : d3);
    int s = sp[le] + g * NODES;
    int d = dp[le] + g * NODES;
    int pos = atomicAdd(&cursor[d], 1);
    csr[pos] = s;
}

// ---------------- SpMM gather, bf16 in / bf16 out, fp32 accum ----------------
// IND = input dwords per row, INLD = input dword stride, OUTLD = output dword stride
template <int IND, int INLD, int OUTLD>
__global__ void k_spmm_bf(const unsigned* __restrict__ h, unsigned* __restrict__ agg,
                          const int* __restrict__ row_ptr, const int* __restrict__ csr,
                          const float* __restrict__ inv_out, const float* __restrict__ inv_in) {
    constexpr int CH = (IND + 63) / 64;
    int n = blockIdx.x * 4 + (threadIdx.x >> 6);
    int lane = threadIdx.x & 63;
    float acc[CH][2];
    #pragma unroll
    for (int c = 0; c < CH; c++) { acc[c][0] = 0.f; acc[c][1] = 0.f; }
    int k0 = row_ptr[n], k1 = row_ptr[n + 1];
    for (int k = k0; k < k1; k++) {
        int s = csr[k];
        float w = inv_out[s];
        const unsigned* hr = h + (size_t)s * INLD;
        #pragma unroll
        for (int c = 0; c < CH; c++) {
            int idx = c * 64 + lane;
            if (idx < IND) {
                unsigned u = hr[idx];
                acc[c][0] += bf_lo(u) * w;
                acc[c][1] += bf_hi(u) * w;
            }
        }
    }
    float wi = inv_in[n];
    unsigned* ar = agg + (size_t)n * OUTLD;
    #pragma unroll
    for (int c = 0; c < CH; c++) {
        int idx = c * 64 + lane;
        if (idx < IND) {
            ar[idx] = (unsigned)f2bf(acc[c][0] * wi) | ((unsigned)f2bf(acc[c][1] * wi) << 16);
        }
    }
    for (int idx = IND + lane; idx < OUTLD; idx += 64) ar[idx] = 0;  // zero pad
}

// ---------------- W prep: fp32 W[K][304] -> bf16 Wt[304][Kpad] (zero-padded K) ----
__global__ void k_prepw(const float* __restrict__ W, short* __restrict__ Wt,
                        int K, int Kpad) {
    int id = blockIdx.x * 256 + threadIdx.x;
    if (id >= D_H * Kpad) return;
    int n = id / Kpad, k = id - n * Kpad;
    short v = 0;
    if (k < K) v = (short)f2bf(W[k * D_H + n]);
    Wt[id] = v;
}

// ---------------- bf16 MFMA GEMM: C[M x 304] = relu(A[M x K] @ Wt^T + bias) -----
// A: bf16, lda stride; Wt: bf16 [304][K]; C: bf16, stride 304. K % 32 == 0.
__global__ __launch_bounds__(256, 2) void k_gemm_mfma(
    const short* __restrict__ A, int lda,
    const short* __restrict__ Wt,
    const float* __restrict__ bias,
    short* __restrict__ C, int M, int K) {
    __shared__ short As[128 * LDT];
    __shared__ short Bs[304 * LDT];
    int tid = threadIdx.x;
    int wv = tid >> 6, lane = tid & 63;
    int quad = lane >> 4, lrow = lane & 15;
    int bm = blockIdx.x * 128;

    f32x4 acc[2][19];
    #pragma unroll
    for (int r = 0; r < 2; r++)
        #pragma unroll
        for (int t = 0; t < 19; t++) acc[r][t] = (f32x4){0.f, 0.f, 0.f, 0.f};

    for (int kt = 0; kt < K; kt += 32) {
        // stage A tile: 128 rows x 32 cols bf16 (512 16B chunks)
        #pragma unroll
        for (int j = 0; j < 2; j++) {
            int q = j * 256 + tid;
            int row = q >> 2, off = q & 3;
            int grow = bm + row;
            uint4 v = make_uint4(0u, 0u, 0u, 0u);
            if (grow < M) v = *(const uint4*)(A + (size_t)grow * lda + kt + off * 8);
            *(uint4*)(&As[row * LDT + off * 8]) = v;
        }
        // stage B tile: 304 rows x 32 cols bf16 (1216 16B chunks)
        for (int q = tid; q < 1216; q += 256) {
            int n = q >> 2, off = q & 3;
            uint4 v = *(const uint4*)(Wt + (size_t)n * K + kt + off * 8);
            *(uint4*)(&Bs[n * LDT + off * 8]) = v;
        }
        __syncthreads();
        short8 a0 = *(const short8*)(&As[(wv * 32 + lrow) * LDT + quad * 8]);
        short8 a1 = *(const short8*)(&As[(wv * 32 + 16 + lrow) * LDT + quad * 8]);
        #pragma unroll
        for (int t = 0; t < 19; t++) {
            short8 b = *(const short8*)(&Bs[(t * 16 + lrow) * LDT + quad * 8]);
            acc[0][t] = __builtin_amdgcn_mfma_f32_16x16x32_bf16(a0, b, acc[0][t], 0, 0, 0);
            acc[1][t] = __builtin_amdgcn_mfma_f32_16x16x32_bf16(a1, b, acc[1][t], 0, 0, 0);
        }
        __syncthreads();
    }
    // epilogue: C/D layout col=lane&15, row=(lane>>4)*4+reg
    #pragma unroll
    for (int t = 0; t < 19; t++) {
        int col = t * 16 + lrow;
        float bv = bias[col];
        #pragma unroll
        for (int r = 0; r < 2; r++) {
            int rbase = bm + wv * 32 + r * 16 + quad * 4;
            #pragma unroll
            for (int g = 0; g < 4; g++) {
                int row = rbase + g;
                if (row < M) {
                    float v = fmaxf(acc[r][t][g] + bv, 0.f);
                    C[(size_t)row * D_H + col] = (short)f2bf(v);
                }
            }
        }
    }
}

// ---------------- column max-pool over bf16 h (LD 304 -> 152 dwords) ----------
__global__ void k_pool_bf(const unsigned* __restrict__ h, int* __restrict__ pooled) {
    int t = threadIdx.x;   // 256, active < 152
    if (t >= 152) return;
    int r0 = blockIdx.x * 256;
    int r1 = min(r0 + 256, TOTN);
    float m0 = 0.f, m1 = 0.f;   // relu outputs >= 0
    for (int r = r0; r < r1; r++) {
        unsigned u = h[(size_t)r * 152 + t];
        m0 = fmaxf(m0, bf_lo(u));
        m1 = fmaxf(m1, bf_hi(u));
    }
    atomicMax(&pooled[2 * t],     __float_as_int(m0));
    atomicMax(&pooled[2 * t + 1], __float_as_int(m1));
}

// ---------------- MLP head: 304 -> 128 -> 64 -> 1, sigmoid ----------------
__global__ void k_mlp(const int* __restrict__ pooled_i,
                      const float* __restrict__ fW1, const float* __restrict__ fb1,
                      const float* __restrict__ fW2, const float* __restrict__ fb2,
                      const float* __restrict__ fW3, const float* __restrict__ fb3,
                      float* __restrict__ out) {
    __shared__ float p[D_H];
    __shared__ float z1[128];
    __shared__ float z2[64];
    int t = threadIdx.x;  // 320
    if (t < D_H) p[t] = __int_as_float(pooled_i[t]);
    __syncthreads();
    if (t < 128) {
        float acc = fb1[t];
        for (int k = 0; k < D_H; k++) acc += p[k] * fW1[k * 128 + t];
        z1[t] = fmaxf(acc, 0.f);
    }
    __syncthreads();
    if (t < 64) {
        float acc = fb2[t];
        for (int k = 0; k < 128; k++) acc += z1[k] * fW2[k * 64 + t];
        z2[t] = fmaxf(acc, 0.f);
    }
    __syncthreads();
    if (t == 0) {
        float acc = fb3[0];
        for (int k = 0; k < 64; k++) acc += z2[k] * fW3[k];
        out[0] = 1.f / (1.f + expf(-acc));
    }
}

extern "C" void kernel_launch(void* const* d_in, const int* in_sizes, int n_in,
                              void* d_out, int out_size, void* d_ws, size_t ws_size,
                              hipStream_t stream) {
    const float* x1 = (const float*)d_in[0];
    const float* x2 = (const float*)d_in[1];
    const float* x3 = (const float*)d_in[2];
    const int* src1 = (const int*)d_in[3];
    const int* dst1 = (const int*)d_in[4];
    const int* src2 = (const int*)d_in[5];
    const int* dst2 = (const int*)d_in[6];
    const int* src3 = (const int*)d_in[7];
    const int* dst3 = (const int*)d_in[8];
    const float* W1 = (const float*)d_in[9];
    const float* b1 = (const float*)d_in[10];
    const float* W2 = (const float*)d_in[11];
    const float* b2 = (const float*)d_in[12];
    const float* W3 = (const float*)d_in[13];
    const float* b3 = (const float*)d_in[14];
    const float* fW1 = (const float*)d_in[15];
    const float* fb1 = (const float*)d_in[16];
    const float* fW2 = (const float*)d_in[17];
    const float* fb2 = (const float*)d_in[18];
    const float* fW3 = (const float*)d_in[19];
    const float* fb3 = (const float*)d_in[20];
    float* out = (float*)d_out;

    char* w = (char*)d_ws;
    unsigned* X  = (unsigned*)w; w += (size_t)TOTN * D_IN * 2;        // bf16 60000x128
    unsigned* P  = (unsigned*)w; w += (size_t)TOTN * 320 * 2;         // bf16 60000x320 (or x128)
    unsigned* Q  = (unsigned*)w; w += (size_t)TOTN * D_H * 2;         // bf16 60000x304
    short* Wt1   = (short*)w;    w += (size_t)D_H * 128 * 2;
    short* Wt2   = (short*)w;    w += (size_t)D_H * 320 * 2;
    short* Wt3   = (short*)w;    w += (size_t)D_H * 320 * 2;
    float* inv_out = (float*)w;  w += (size_t)TOTN * 4;
    float* inv_in  = (float*)w;  w += (size_t)TOTN * 4;
    int* out_cnt   = (int*)w;    w += (size_t)TOTN * 4;
    int* in_cnt    = (int*)w;    w += (size_t)TOTN * 4;
    int* row_ptr   = (int*)w;    w += (size_t)(TOTN + 4) * 4;
    int* cursor    = (int*)w;    w += (size_t)TOTN * 4;
    int* csr       = (int*)w;    w += (size_t)TOTE * 4;
    int* pooled    = (int*)w;    w += 320 * 4;

    hipMemsetAsync(out_cnt, 0, 2 * (size_t)TOTN * 4, stream);  // out_cnt + in_cnt
    hipMemsetAsync(pooled, 0, D_H * 4, stream);

    k_pack<<<(3 * NODES * D_IN / 2 + 255) / 256, 256, 0, stream>>>(
        (const float2*)x1, (const float2*)x2, (const float2*)x3, X);
    k_deg<<<(TOTE + 255) / 256, 256, 0, stream>>>(src1, dst1, src2, dst2, src3, dst3,
                                                  out_cnt, in_cnt);
    k_inv<<<(TOTN + 255) / 256, 256, 0, stream>>>(out_cnt, in_cnt, inv_out, inv_in);
    k_scan<<<1, 1024, 0, stream>>>(in_cnt, row_ptr, cursor);
    k_fill<<<(TOTE + 255) / 256, 256, 0, stream>>>(src1, dst1, src2, dst2, src3, dst3,
                                                   cursor, csr);
    k_prepw<<<(D_H * 128 + 255) / 256, 256, 0, stream>>>(W1, Wt1, 128, 128);
    k_prepw<<<(D_H * 320 + 255) / 256, 256, 0, stream>>>(W2, Wt2, 304, 320);
    k_prepw<<<(D_H * 320 + 255) / 256, 256, 0, stream>>>(W3, Wt3, 304, 320);

    int ggrid = (TOTN + 127) / 128;  // 469

    // layer 1: X(128) -> SpMM -> GEMM(K=128) -> Q(304)
    k_spmm_bf<64, 64, 64><<<TOTN / 4, 256, 0, stream>>>(X, P, row_ptr, csr, inv_out, inv_in);
    k_gemm_mfma<<<ggrid, 256, 0, stream>>>((const short*)P, 128, Wt1, b1, (short*)Q, TOTN, 128);
    // layer 2: Q(304) -> SpMM(pad 320) -> GEMM(K=320) -> Q
    k_spmm_bf<152, 152, 160><<<TOTN / 4, 256, 0, stream>>>(Q, P, row_ptr, csr, inv_out, inv_in);
    k_gemm_mfma<<<ggrid, 256, 0, stream>>>((const short*)P, 320, Wt2, b2, (short*)Q, TOTN, 320);
    // layer 3
    k_spmm_bf<152, 152, 160><<<TOTN / 4, 256, 0, stream>>>(Q, P, row_ptr, csr, inv_out, inv_in);
    k_gemm_mfma<<<ggrid, 256, 0, stream>>>((const short*)P, 320, Wt3, b3, (short*)Q, TOTN, 320);

    k_pool_bf<<<(TOTN + 255) / 256, 256, 0, stream>>>(Q, pooled);
    k_mlp<<<1, 320, 0, stream>>>(pooled, fW1, fb1, fW2, fb2, fW3, fb3, out);
}

// Round 3
// 711.449 us; speedup vs baseline: 2.3575x; 1.2775x over previous
//
#include <hip/hip_runtime.h>
#include <hip/hip_bf16.h>
#include <math.h>

#define NODES 20000
#define EDGES 320000
#define NB 3
#define TOTN (NODES * NB)   // 60000
#define TOTE (EDGES * NB)   // 960000
#define D_IN 128
#define D_H 304
#define LDT 40              // LDS row stride (shorts) — breaks pow2 bank pattern
#define SCAN_B 59           // ceil(60000/1024)

typedef __attribute__((ext_vector_type(8))) short short8;
typedef __attribute__((ext_vector_type(4))) float f32x4;
typedef __attribute__((ext_vector_type(2))) float f32x2;

__device__ __forceinline__ unsigned short f2bf(float f) {
    unsigned u = __float_as_uint(f);
    unsigned r = (u + 0x7fffu + ((u >> 16) & 1u)) >> 16;   // RNE
    return (unsigned short)r;
}
__device__ __forceinline__ unsigned pack_bf2(float a, float b) {
    return (unsigned)f2bf(a) | ((unsigned)f2bf(b) << 16);
}

// ---------------- pack x1|x2|x3 fp32 -> X fp8 (60000 x 128) ----------------
__global__ void k_pack8(const float4* __restrict__ x1, const float4* __restrict__ x2,
                        const float4* __restrict__ x3, unsigned* __restrict__ q) {
    const int per = NODES * D_IN / 4;  // float4s per graph = out dwords per graph
    int i = blockIdx.x * 256 + threadIdx.x;
    if (i >= 3 * per) return;
    const float4* s; int j;
    if (i < per)          { s = x1; j = i; }
    else if (i < 2 * per) { s = x2; j = i - per; }
    else                  { s = x3; j = i - 2 * per; }
    float4 v = s[j];
    int p = __builtin_amdgcn_cvt_pk_fp8_f32(v.x, v.y, 0, false);
    p = __builtin_amdgcn_cvt_pk_fp8_f32(v.z, v.w, p, true);
    q[i] = (unsigned)p;
}

// ---------------- degree counting ----------------
__global__ void k_deg(const int* __restrict__ s1, const int* __restrict__ d1,
                      const int* __restrict__ s2, const int* __restrict__ d2,
                      const int* __restrict__ s3, const int* __restrict__ d3,
                      int* __restrict__ out_cnt, int* __restrict__ in_cnt) {
    int e = blockIdx.x * 256 + threadIdx.x;
    if (e >= TOTE) return;
    int g = e / EDGES;
    int le = e - g * EDGES;
    const int* sp = (g == 0) ? s1 : ((g == 1) ? s2 : s3);
    const int* dp = (g == 0) ? d1 : ((g == 1) ? d2 : d3);
    int s = sp[le] + g * NODES;
    int d = dp[le] + g * NODES;
    atomicAdd(&out_cnt[s], 1);
    atomicAdd(&in_cnt[d], 1);
}

__global__ void k_inv(const int* __restrict__ out_cnt, const int* __restrict__ in_cnt,
                      float* __restrict__ inv_out, float* __restrict__ inv_in) {
    int n = blockIdx.x * 256 + threadIdx.x;
    if (n >= TOTN) return;
    inv_out[n] = 1.0f / sqrtf((float)max(out_cnt[n], 1));
    inv_in[n]  = 1.0f / sqrtf((float)max(in_cnt[n], 1));
}

// ---------------- parallel scan: A (per-block excl + total), B (scan totals), C (apply) ----
__global__ void k_scanA(const int* __restrict__ cnt, int* __restrict__ excl,
                        int* __restrict__ btot) {
    __shared__ int wsum[16];
    int b = blockIdx.x, t = threadIdx.x;
    int i = b * 1024 + t;
    int lane = t & 63, wid = t >> 6;
    int v = (i < TOTN) ? cnt[i] : 0;
    int sv = v;
    #pragma unroll
    for (int o = 1; o < 64; o <<= 1) {
        int u = __shfl_up(sv, o, 64);
        if (lane >= o) sv += u;
    }
    if (lane == 63) wsum[wid] = sv;
    __syncthreads();
    if (t < 16) {
        int w = wsum[t];
        #pragma unroll
        for (int o = 1; o < 16; o <<= 1) {
            int u = __shfl_up(w, o, 16);
            if (t >= o) w += u;
        }
        wsum[t] = w;
    }
    __syncthreads();
    int wbase = (wid > 0) ? wsum[wid - 1] : 0;
    if (i < TOTN) excl[i] = wbase + sv - v;
    if (t == 0) btot[b] = wsum[15];
}

__global__ void k_scanB(const int* __restrict__ btot, int* __restrict__ boff) {
    int t = threadIdx.x;  // 64
    int v = (t < SCAN_B) ? btot[t] : 0;
    int sv = v;
    #pragma unroll
    for (int o = 1; o < 64; o <<= 1) {
        int u = __shfl_up(sv, o, 64);
        if (t >= o) sv += u;
    }
    if (t < SCAN_B) boff[t] = sv - v;  // exclusive
}

__global__ void k_scanC(const int* __restrict__ excl, const int* __restrict__ boff,
                        int* __restrict__ row_ptr, int* __restrict__ cursor) {
    int i = blockIdx.x * 1024 + threadIdx.x;
    if (i < TOTN) {
        int v = excl[i] + boff[i >> 10];
        row_ptr[i] = v;
        cursor[i] = v;
    }
    if (i == 0) row_ptr[TOTN] = TOTE;  // sum of in-degrees is exactly #edges
}

// ---------------- CSR fill (incoming edges grouped by dst) ----------------
__global__ void k_fill(const int* __restrict__ s1, const int* __restrict__ d1,
                       const int* __restrict__ s2, const int* __restrict__ d2,
                       const int* __restrict__ s3, const int* __restrict__ d3,
                       int* __restrict__ cursor, int* __restrict__ csr) {
    int e = blockIdx.x * 256 + threadIdx.x;
    if (e >= TOTE) return;
    int g = e / EDGES;
    int le = e - g * EDGES;
    const int* sp = (g == 0) ? s1 : ((g == 1) ? s2 : s3);
    const int* dp = (g == 0) ? d1 : ((g == 1) ? d2 : d3);
    int s = sp[le] + g * NODES;
    int d = dp[le] + g * NODES;
    int pos = atomicAdd(&cursor[d], 1);
    csr[pos] = s;
}

// ---------------- SpMM gather, fp8 in / bf16 out, fp32 accum, edge-unroll x2 ----
// IND = input dwords per row (4 fp8 each), OUTLD = output dword stride (2 bf16 each)
template <int IND, int OUTLD>
__global__ void k_spmm_f8(const unsigned* __restrict__ h, unsigned* __restrict__ agg,
                          const int* __restrict__ row_ptr, const int* __restrict__ csr,
                          const float* __restrict__ inv_out, const float* __restrict__ inv_in) {
    constexpr int CH = (IND + 63) / 64;
    int n = blockIdx.x * 4 + (threadIdx.x >> 6);
    int lane = threadIdx.x & 63;
    float acc[CH][4];
    #pragma unroll
    for (int c = 0; c < CH; c++)
        #pragma unroll
        for (int j = 0; j < 4; j++) acc[c][j] = 0.f;
    int k0 = row_ptr[n], k1 = row_ptr[n + 1];
    int k = k0;
    for (; k + 2 <= k1; k += 2) {
        int s0 = csr[k], s1 = csr[k + 1];
        float w0 = inv_out[s0], w1 = inv_out[s1];
        const unsigned* r0 = h + (size_t)s0 * IND;
        const unsigned* r1 = h + (size_t)s1 * IND;
        #pragma unroll
        for (int c = 0; c < CH; c++) {
            int idx = c * 64 + lane;
            if (idx < IND) {
                unsigned u0 = r0[idx], u1 = r1[idx];
                f32x2 a0 = __builtin_amdgcn_cvt_pk_f32_fp8(u0, false);
                f32x2 b0 = __builtin_amdgcn_cvt_pk_f32_fp8(u0, true);
                f32x2 a1 = __builtin_amdgcn_cvt_pk_f32_fp8(u1, false);
                f32x2 b1 = __builtin_amdgcn_cvt_pk_f32_fp8(u1, true);
                acc[c][0] += a0[0] * w0 + a1[0] * w1;
                acc[c][1] += a0[1] * w0 + a1[1] * w1;
                acc[c][2] += b0[0] * w0 + b1[0] * w1;
                acc[c][3] += b0[1] * w0 + b1[1] * w1;
            }
        }
    }
    if (k < k1) {
        int s0 = csr[k];
        float w0 = inv_out[s0];
        const unsigned* r0 = h + (size_t)s0 * IND;
        #pragma unroll
        for (int c = 0; c < CH; c++) {
            int idx = c * 64 + lane;
            if (idx < IND) {
                unsigned u0 = r0[idx];
                f32x2 a0 = __builtin_amdgcn_cvt_pk_f32_fp8(u0, false);
                f32x2 b0 = __builtin_amdgcn_cvt_pk_f32_fp8(u0, true);
                acc[c][0] += a0[0] * w0;
                acc[c][1] += a0[1] * w0;
                acc[c][2] += b0[0] * w0;
                acc[c][3] += b0[1] * w0;
            }
        }
    }
    float wi = inv_in[n];
    unsigned* ar = agg + (size_t)n * OUTLD;
    #pragma unroll
    for (int c = 0; c < CH; c++) {
        int idx = c * 64 + lane;
        if (idx < IND) {
            ar[2 * idx]     = pack_bf2(acc[c][0] * wi, acc[c][1] * wi);
            ar[2 * idx + 1] = pack_bf2(acc[c][2] * wi, acc[c][3] * wi);
        }
    }
    for (int idx = 2 * IND + lane; idx < OUTLD; idx += 64) ar[idx] = 0;  // zero pad
}

// ---------------- W prep: fp32 W[K][304] -> bf16 Wt[304][Kpad] (zero-padded K) ----
__global__ void k_prepw(const float* __restrict__ W, short* __restrict__ Wt,
                        int K, int Kpad) {
    int id = blockIdx.x * 256 + threadIdx.x;
    if (id >= D_H * Kpad) return;
    int n = id / Kpad, k = id - n * Kpad;
    short v = 0;
    if (k < K) v = (short)f2bf(W[k * D_H + n]);
    Wt[id] = v;
}

// ---------------- bf16 MFMA GEMM: relu(A[MxK] @ Wt^T + bias) -> fp8 or bf16 -----
// A: bf16, lda stride; Wt: bf16 [304][K]; K % 32 == 0.
// OUT8: C8 fp8 rows of 304 B; else C bf16 rows of 304 shorts.
template <bool OUT8>
__global__ __launch_bounds__(256, 2) void k_gemm_mfma(
    const short* __restrict__ A, int lda,
    const short* __restrict__ Wt,
    const float* __restrict__ bias,
    short* __restrict__ C, unsigned char* __restrict__ C8, int M, int K) {
    __shared__ short As[128 * LDT];
    __shared__ short Bs[304 * LDT];
    int tid = threadIdx.x;
    int wv = tid >> 6, lane = tid & 63;
    int quad = lane >> 4, lrow = lane & 15;
    int bm = blockIdx.x * 128;

    f32x4 acc[2][19];
    #pragma unroll
    for (int r = 0; r < 2; r++)
        #pragma unroll
        for (int t = 0; t < 19; t++) acc[r][t] = (f32x4){0.f, 0.f, 0.f, 0.f};

    for (int kt = 0; kt < K; kt += 32) {
        #pragma unroll
        for (int j = 0; j < 2; j++) {
            int q = j * 256 + tid;
            int row = q >> 2, off = q & 3;
            int grow = bm + row;
            uint4 v = make_uint4(0u, 0u, 0u, 0u);
            if (grow < M) v = *(const uint4*)(A + (size_t)grow * lda + kt + off * 8);
            *(uint4*)(&As[row * LDT + off * 8]) = v;
        }
        for (int q = tid; q < 1216; q += 256) {
            int n = q >> 2, off = q & 3;
            uint4 v = *(const uint4*)(Wt + (size_t)n * K + kt + off * 8);
            *(uint4*)(&Bs[n * LDT + off * 8]) = v;
        }
        __syncthreads();
        short8 a0 = *(const short8*)(&As[(wv * 32 + lrow) * LDT + quad * 8]);
        short8 a1 = *(const short8*)(&As[(wv * 32 + 16 + lrow) * LDT + quad * 8]);
        #pragma unroll
        for (int t = 0; t < 19; t++) {
            short8 b = *(const short8*)(&Bs[(t * 16 + lrow) * LDT + quad * 8]);
            acc[0][t] = __builtin_amdgcn_mfma_f32_16x16x32_bf16(a0, b, acc[0][t], 0, 0, 0);
            acc[1][t] = __builtin_amdgcn_mfma_f32_16x16x32_bf16(a1, b, acc[1][t], 0, 0, 0);
        }
        __syncthreads();
    }
    // epilogue: C/D layout col=lane&15, row=(lane>>4)*4+reg
    #pragma unroll
    for (int t = 0; t < 19; t++) {
        int col = t * 16 + lrow;
        float bv = bias[col];
        #pragma unroll
        for (int r = 0; r < 2; r++) {
            int rbase = bm + wv * 32 + r * 16 + quad * 4;
            #pragma unroll
            for (int g = 0; g < 4; g++) {
                int row = rbase + g;
                if (row < M) {
                    float v = fmaxf(acc[r][t][g] + bv, 0.f);
                    if (OUT8) {
                        int p = __builtin_amdgcn_cvt_pk_fp8_f32(v, v, 0, false);
                        C8[(size_t)row * 304 + col] = (unsigned char)(p & 0xff);
                    } else {
                        C[(size_t)row * D_H + col] = (short)f2bf(v);
                    }
                }
            }
        }
    }
}

// ---------------- column max-pool over bf16 h (stride 152 dwords) ----------
__global__ void k_pool_bf(const unsigned* __restrict__ h, int* __restrict__ pooled) {
    int t = threadIdx.x;   // 256, active < 152
    if (t >= 152) return;
    int r0 = blockIdx.x * 256;
    int r1 = min(r0 + 256, TOTN);
    float m0 = 0.f, m1 = 0.f;   // relu outputs >= 0
    for (int r = r0; r < r1; r++) {
        unsigned u = h[(size_t)r * 152 + t];
        m0 = fmaxf(m0, __uint_as_float(u << 16));
        m1 = fmaxf(m1, __uint_as_float(u & 0xffff0000u));
    }
    atomicMax(&pooled[2 * t],     __float_as_int(m0));
    atomicMax(&pooled[2 * t + 1], __float_as_int(m1));
}

// ---------------- MLP head: 304 -> 128 -> 64 -> 1, sigmoid ----------------
__global__ void k_mlp(const int* __restrict__ pooled_i,
                      const float* __restrict__ fW1, const float* __restrict__ fb1,
                      const float* __restrict__ fW2, const float* __restrict__ fb2,
                      const float* __restrict__ fW3, const float* __restrict__ fb3,
                      float* __restrict__ out) {
    __shared__ float p[D_H];
    __shared__ float z1[128];
    __shared__ float z2[64];
    int t = threadIdx.x;  // 320
    if (t < D_H) p[t] = __int_as_float(pooled_i[t]);
    __syncthreads();
    if (t < 128) {
        float acc = fb1[t];
        for (int k = 0; k < D_H; k++) acc += p[k] * fW1[k * 128 + t];
        z1[t] = fmaxf(acc, 0.f);
    }
    __syncthreads();
    if (t < 64) {
        float acc = fb2[t];
        for (int k = 0; k < 128; k++) acc += z1[k] * fW2[k * 64 + t];
        z2[t] = fmaxf(acc, 0.f);
    }
    __syncthreads();
    if (t == 0) {
        float acc = fb3[0];
        for (int k = 0; k < 64; k++) acc += z2[k] * fW3[k];
        out[0] = 1.f / (1.f + expf(-acc));
    }
}

extern "C" void kernel_launch(void* const* d_in, const int* in_sizes, int n_in,
                              void* d_out, int out_size, void* d_ws, size_t ws_size,
                              hipStream_t stream) {
    const float* x1 = (const float*)d_in[0];
    const float* x2 = (const float*)d_in[1];
    const float* x3 = (const float*)d_in[2];
    const int* src1 = (const int*)d_in[3];
    const int* dst1 = (const int*)d_in[4];
    const int* src2 = (const int*)d_in[5];
    const int* dst2 = (const int*)d_in[6];
    const int* src3 = (const int*)d_in[7];
    const int* dst3 = (const int*)d_in[8];
    const float* W1 = (const float*)d_in[9];
    const float* b1 = (const float*)d_in[10];
    const float* W2 = (const float*)d_in[11];
    const float* b2 = (const float*)d_in[12];
    const float* W3 = (const float*)d_in[13];
    const float* b3 = (const float*)d_in[14];
    const float* fW1 = (const float*)d_in[15];
    const float* fb1 = (const float*)d_in[16];
    const float* fW2 = (const float*)d_in[17];
    const float* fb2 = (const float*)d_in[18];
    const float* fW3 = (const float*)d_in[19];
    const float* fb3 = (const float*)d_in[20];
    float* out = (float*)d_out;

    char* w = (char*)d_ws;
    unsigned* X8 = (unsigned*)w; w += (size_t)TOTN * 32 * 4;          // fp8 60000x128
    unsigned* Q8 = (unsigned*)w; w += (size_t)TOTN * 76 * 4;          // fp8 60000x304
    unsigned* P  = (unsigned*)w; w += (size_t)TOTN * 160 * 4;         // bf16 60000x320
    unsigned* Qb = (unsigned*)w; w += (size_t)TOTN * 152 * 4;         // bf16 60000x304
    short* Wt1   = (short*)w;    w += (size_t)D_H * 128 * 2;
    short* Wt2   = (short*)w;    w += (size_t)D_H * 320 * 2;
    short* Wt3   = (short*)w;    w += (size_t)D_H * 320 * 2;
    float* inv_out = (float*)w;  w += (size_t)TOTN * 4;
    float* inv_in  = (float*)w;  w += (size_t)TOTN * 4;
    int* out_cnt   = (int*)w;    w += (size_t)TOTN * 4;
    int* in_cnt    = (int*)w;    w += (size_t)TOTN * 4;
    int* row_ptr   = (int*)w;    w += (size_t)(TOTN + 4) * 4;
    int* cursor    = (int*)w;    w += (size_t)TOTN * 4;
    int* csr       = (int*)w;    w += (size_t)TOTE * 4;
    int* excl      = (int*)w;    w += (size_t)TOTN * 4;
    int* btot      = (int*)w;    w += 64 * 4;
    int* boff      = (int*)w;    w += 64 * 4;
    int* pooled    = (int*)w;    w += 320 * 4;

    hipMemsetAsync(out_cnt, 0, 2 * (size_t)TOTN * 4, stream);  // out_cnt + in_cnt
    hipMemsetAsync(pooled, 0, D_H * 4, stream);

    k_pack8<<<(3 * NODES * D_IN / 4 + 255) / 256, 256, 0, stream>>>(
        (const float4*)x1, (const float4*)x2, (const float4*)x3, X8);
    k_deg<<<(TOTE + 255) / 256, 256, 0, stream>>>(src1, dst1, src2, dst2, src3, dst3,
                                                  out_cnt, in_cnt);
    k_inv<<<(TOTN + 255) / 256, 256, 0, stream>>>(out_cnt, in_cnt, inv_out, inv_in);
    k_scanA<<<SCAN_B, 1024, 0, stream>>>(in_cnt, excl, btot);
    k_scanB<<<1, 64, 0, stream>>>(btot, boff);
    k_scanC<<<SCAN_B, 1024, 0, stream>>>(excl, boff, row_ptr, cursor);
    k_fill<<<(TOTE + 255) / 256, 256, 0, stream>>>(src1, dst1, src2, dst2, src3, dst3,
                                                   cursor, csr);
    k_prepw<<<(D_H * 128 + 255) / 256, 256, 0, stream>>>(W1, Wt1, 128, 128);
    k_prepw<<<(D_H * 320 + 255) / 256, 256, 0, stream>>>(W2, Wt2, 304, 320);
    k_prepw<<<(D_H * 320 + 255) / 256, 256, 0, stream>>>(W3, Wt3, 304, 320);

    int ggrid = (TOTN + 127) / 128;  // 469

    // layer 1: X8(128 fp8) -> SpMM -> P(bf16,128) -> GEMM(K=128) -> Q8(fp8 304)
    k_spmm_f8<32, 64><<<TOTN / 4, 256, 0, stream>>>(X8, P, row_ptr, csr, inv_out, inv_in);
    k_gemm_mfma<true><<<ggrid, 256, 0, stream>>>((const short*)P, 128, Wt1, b1,
                                                 nullptr, (unsigned char*)Q8, TOTN, 128);
    // layer 2
    k_spmm_f8<76, 160><<<TOTN / 4, 256, 0, stream>>>(Q8, P, row_ptr, csr, inv_out, inv_in);
    k_gemm_mfma<true><<<ggrid, 256, 0, stream>>>((const short*)P, 320, Wt2, b2,
                                                 nullptr, (unsigned char*)Q8, TOTN, 320);
    // layer 3 -> bf16 Qb for pooling
    k_spmm_f8<76, 160><<<TOTN / 4, 256, 0, stream>>>(Q8, P, row_ptr, csr, inv_out, inv_in);
    k_gemm_mfma<false><<<ggrid, 256, 0, stream>>>((const short*)P, 320, Wt3, b3,
                                                  (short*)Qb, nullptr, TOTN, 320);

    k_pool_bf<<<(TOTN + 255) / 256, 256, 0, stream>>>(Qb, pooled);
    k_mlp<<<1, 320, 0, stream>>>(pooled, fW1, fb1, fW2, fb2, fW3, fb3, out);
}

// Round 4
// 628.012 us; speedup vs baseline: 2.6707x; 1.1329x over previous
//
#include <hip/hip_runtime.h>
#include <hip/hip_bf16.h>
#include <math.h>

#define NODES 20000
#define EDGES 320000
#define NB 3
#define TOTN (NODES * NB)   // 60000
#define TOTE (EDGES * NB)   // 960000
#define D_IN 128
#define D_H 304
#define LDT 40              // LDS row stride (shorts) — breaks pow2 bank pattern
#define SCAN_B 59           // ceil(60000/1024)

typedef __attribute__((ext_vector_type(8))) short short8;
typedef __attribute__((ext_vector_type(4))) float f32x4;
typedef __attribute__((ext_vector_type(2))) float f32x2;

__device__ __forceinline__ unsigned short f2bf(float f) {
    unsigned u = __float_as_uint(f);
    unsigned r = (u + 0x7fffu + ((u >> 16) & 1u)) >> 16;   // RNE
    return (unsigned short)r;
}
__device__ __forceinline__ unsigned pack_bf2(float a, float b) {
    return (unsigned)f2bf(a) | ((unsigned)f2bf(b) << 16);
}

// ------- pack x1|x2|x3 fp32 -> X fp8 (60000 x 128), pre-scaled by inv_out -------
__global__ void k_pack8(const float4* __restrict__ x1, const float4* __restrict__ x2,
                        const float4* __restrict__ x3, const float* __restrict__ inv_out,
                        unsigned* __restrict__ q) {
    const int per = NODES * D_IN / 4;  // out dwords per graph (32 per row)
    int i = blockIdx.x * 256 + threadIdx.x;
    if (i >= 3 * per) return;
    const float4* s; int j;
    if (i < per)          { s = x1; j = i; }
    else if (i < 2 * per) { s = x2; j = i - per; }
    else                  { s = x3; j = i - 2 * per; }
    float4 v = s[j];
    float sc = inv_out[i >> 5];   // 32 dwords per row, global node id
    int p = __builtin_amdgcn_cvt_pk_fp8_f32(v.x * sc, v.y * sc, 0, false);
    p = __builtin_amdgcn_cvt_pk_fp8_f32(v.z * sc, v.w * sc, p, true);
    q[i] = (unsigned)p;
}

// ---------------- degree counting ----------------
__global__ void k_deg(const int* __restrict__ s1, const int* __restrict__ d1,
                      const int* __restrict__ s2, const int* __restrict__ d2,
                      const int* __restrict__ s3, const int* __restrict__ d3,
                      int* __restrict__ out_cnt, int* __restrict__ in_cnt) {
    int e = blockIdx.x * 256 + threadIdx.x;
    if (e >= TOTE) return;
    int g = e / EDGES;
    int le = e - g * EDGES;
    const int* sp = (g == 0) ? s1 : ((g == 1) ? s2 : s3);
    const int* dp = (g == 0) ? d1 : ((g == 1) ? d2 : d3);
    int s = sp[le] + g * NODES;
    int d = dp[le] + g * NODES;
    atomicAdd(&out_cnt[s], 1);
    atomicAdd(&in_cnt[d], 1);
}

__global__ void k_inv(const int* __restrict__ out_cnt, const int* __restrict__ in_cnt,
                      float* __restrict__ inv_out, float* __restrict__ inv_in) {
    int n = blockIdx.x * 256 + threadIdx.x;
    if (n >= TOTN) return;
    inv_out[n] = 1.0f / sqrtf((float)max(out_cnt[n], 1));
    inv_in[n]  = 1.0f / sqrtf((float)max(in_cnt[n], 1));
}

// ------- parallel scan: A (per-block excl + total), B (scan totals), C (apply) -------
__global__ void k_scanA(const int* __restrict__ cnt, int* __restrict__ excl,
                        int* __restrict__ btot) {
    __shared__ int wsum[16];
    int b = blockIdx.x, t = threadIdx.x;
    int i = b * 1024 + t;
    int lane = t & 63, wid = t >> 6;
    int v = (i < TOTN) ? cnt[i] : 0;
    int sv = v;
    #pragma unroll
    for (int o = 1; o < 64; o <<= 1) {
        int u = __shfl_up(sv, o, 64);
        if (lane >= o) sv += u;
    }
    if (lane == 63) wsum[wid] = sv;
    __syncthreads();
    if (t < 16) {
        int w = wsum[t];
        #pragma unroll
        for (int o = 1; o < 16; o <<= 1) {
            int u = __shfl_up(w, o, 16);
            if (t >= o) w += u;
        }
        wsum[t] = w;
    }
    __syncthreads();
    int wbase = (wid > 0) ? wsum[wid - 1] : 0;
    if (i < TOTN) excl[i] = wbase + sv - v;
    if (t == 0) btot[b] = wsum[15];
}

__global__ void k_scanB(const int* __restrict__ btot, int* __restrict__ boff) {
    int t = threadIdx.x;  // 64
    int v = (t < SCAN_B) ? btot[t] : 0;
    int sv = v;
    #pragma unroll
    for (int o = 1; o < 64; o <<= 1) {
        int u = __shfl_up(sv, o, 64);
        if (t >= o) sv += u;
    }
    if (t < SCAN_B) boff[t] = sv - v;  // exclusive
}

__global__ void k_scanC(const int* __restrict__ excl, const int* __restrict__ boff,
                        int* __restrict__ row_ptr, int* __restrict__ cursor) {
    int i = blockIdx.x * 1024 + threadIdx.x;
    if (i < TOTN) {
        int v = excl[i] + boff[i >> 10];
        row_ptr[i] = v;
        cursor[i] = v;
    }
    if (i == 0) row_ptr[TOTN] = TOTE;  // sum of in-degrees is exactly #edges
}

// ---------------- CSR fill (incoming edges grouped by dst) ----------------
__global__ void k_fill(const int* __restrict__ s1, const int* __restrict__ d1,
                       const int* __restrict__ s2, const int* __restrict__ d2,
                       const int* __restrict__ s3, const int* __restrict__ d3,
                       int* __restrict__ cursor, int* __restrict__ csr) {
    int e = blockIdx.x * 256 + threadIdx.x;
    if (e >= TOTE) return;
    int g = e / EDGES;
    int le = e - g * EDGES;
    const int* sp = (g == 0) ? s1 : ((g == 1) ? s2 : s3);
    const int* dp = (g == 0) ? d1 : ((g == 1) ? d2 : d3);
    int s = sp[le] + g * NODES;
    int d = dp[le] + g * NODES;
    int pos = atomicAdd(&cursor[d], 1);
    csr[pos] = s;
}

// ------- SpMM gather, fp8 (pre-scaled by inv_out) -> bf16, fp32 accum, unroll x4 ----
// IND = input dwords per row, OUTLD = output dword stride, LANES = lanes per node
template <int IND, int OUTLD, int LANES>
__global__ void k_spmm_f8(const unsigned* __restrict__ h, unsigned* __restrict__ agg,
                          const int* __restrict__ row_ptr, const int* __restrict__ csr,
                          const float* __restrict__ inv_in) {
    constexpr int CH = (IND + LANES - 1) / LANES;
    constexpr int NPB = 256 / LANES;
    int n = blockIdx.x * NPB + (threadIdx.x / LANES);
    int lane = threadIdx.x % LANES;
    f32x2 acc[CH][2];
    #pragma unroll
    for (int c = 0; c < CH; c++) {
        acc[c][0] = (f32x2){0.f, 0.f};
        acc[c][1] = (f32x2){0.f, 0.f};
    }
    int k0 = row_ptr[n], k1 = row_ptr[n + 1];
    int k = k0;
    for (; k + 4 <= k1; k += 4) {
        int s0 = csr[k], s1 = csr[k + 1], s2 = csr[k + 2], s3 = csr[k + 3];
        const unsigned* r0 = h + (size_t)s0 * IND;
        const unsigned* r1 = h + (size_t)s1 * IND;
        const unsigned* r2 = h + (size_t)s2 * IND;
        const unsigned* r3 = h + (size_t)s3 * IND;
        #pragma unroll
        for (int c = 0; c < CH; c++) {
            int idx = c * LANES + lane;
            if (idx < IND) {
                unsigned u0 = r0[idx], u1 = r1[idx], u2 = r2[idx], u3 = r3[idx];
                f32x2 lo = __builtin_amdgcn_cvt_pk_f32_fp8(u0, false)
                         + __builtin_amdgcn_cvt_pk_f32_fp8(u1, false)
                         + __builtin_amdgcn_cvt_pk_f32_fp8(u2, false)
                         + __builtin_amdgcn_cvt_pk_f32_fp8(u3, false);
                f32x2 hi = __builtin_amdgcn_cvt_pk_f32_fp8(u0, true)
                         + __builtin_amdgcn_cvt_pk_f32_fp8(u1, true)
                         + __builtin_amdgcn_cvt_pk_f32_fp8(u2, true)
                         + __builtin_amdgcn_cvt_pk_f32_fp8(u3, true);
                acc[c][0] += lo;
                acc[c][1] += hi;
            }
        }
    }
    for (; k < k1; k++) {
        int s0 = csr[k];
        const unsigned* r0 = h + (size_t)s0 * IND;
        #pragma unroll
        for (int c = 0; c < CH; c++) {
            int idx = c * LANES + lane;
            if (idx < IND) {
                unsigned u0 = r0[idx];
                acc[c][0] += __builtin_amdgcn_cvt_pk_f32_fp8(u0, false);
                acc[c][1] += __builtin_amdgcn_cvt_pk_f32_fp8(u0, true);
            }
        }
    }
    float wi = inv_in[n];
    unsigned* ar = agg + (size_t)n * OUTLD;
    #pragma unroll
    for (int c = 0; c < CH; c++) {
        int idx = c * LANES + lane;
        if (idx < IND) {
            uint2 st;
            st.x = pack_bf2(acc[c][0][0] * wi, acc[c][0][1] * wi);
            st.y = pack_bf2(acc[c][1][0] * wi, acc[c][1][1] * wi);
            *(uint2*)(&ar[2 * idx]) = st;
        }
    }
    for (int idx = 2 * IND + lane; idx < OUTLD; idx += LANES) ar[idx] = 0;  // zero pad
}

// ------- W prep: fp32 W[K][304] -> bf16 Wt[304][Kpad] (zero-padded K) -------
__global__ void k_prepw(const float* __restrict__ W, short* __restrict__ Wt,
                        int K, int Kpad) {
    int id = blockIdx.x * 256 + threadIdx.x;
    if (id >= D_H * Kpad) return;
    int n = id / Kpad, k = id - n * Kpad;
    short v = 0;
    if (k < K) v = (short)f2bf(W[k * D_H + n]);
    Wt[id] = v;
}

// ------- bf16 MFMA GEMM: relu(A[MxK] @ Wt^T + bias) -> fp8 (x inv_out) or bf16 ----
template <bool OUT8>
__global__ __launch_bounds__(256, 2) void k_gemm_mfma(
    const short* __restrict__ A, int lda,
    const short* __restrict__ Wt,
    const float* __restrict__ bias,
    const float* __restrict__ inv_out,
    short* __restrict__ C, unsigned char* __restrict__ C8, int M, int K) {
    __shared__ short As[128 * LDT];
    __shared__ short Bs[304 * LDT];
    int tid = threadIdx.x;
    int wv = tid >> 6, lane = tid & 63;
    int quad = lane >> 4, lrow = lane & 15;
    int bm = blockIdx.x * 128;

    f32x4 acc[2][19];
    #pragma unroll
    for (int r = 0; r < 2; r++)
        #pragma unroll
        for (int t = 0; t < 19; t++) acc[r][t] = (f32x4){0.f, 0.f, 0.f, 0.f};

    for (int kt = 0; kt < K; kt += 32) {
        #pragma unroll
        for (int j = 0; j < 2; j++) {
            int q = j * 256 + tid;
            int row = q >> 2, off = q & 3;
            int grow = bm + row;
            uint4 v = make_uint4(0u, 0u, 0u, 0u);
            if (grow < M) v = *(const uint4*)(A + (size_t)grow * lda + kt + off * 8);
            *(uint4*)(&As[row * LDT + off * 8]) = v;
        }
        for (int q = tid; q < 1216; q += 256) {
            int n = q >> 2, off = q & 3;
            uint4 v = *(const uint4*)(Wt + (size_t)n * K + kt + off * 8);
            *(uint4*)(&Bs[n * LDT + off * 8]) = v;
        }
        __syncthreads();
        short8 a0 = *(const short8*)(&As[(wv * 32 + lrow) * LDT + quad * 8]);
        short8 a1 = *(const short8*)(&As[(wv * 32 + 16 + lrow) * LDT + quad * 8]);
        #pragma unroll
        for (int t = 0; t < 19; t++) {
            short8 b = *(const short8*)(&Bs[(t * 16 + lrow) * LDT + quad * 8]);
            acc[0][t] = __builtin_amdgcn_mfma_f32_16x16x32_bf16(a0, b, acc[0][t], 0, 0, 0);
            acc[1][t] = __builtin_amdgcn_mfma_f32_16x16x32_bf16(a1, b, acc[1][t], 0, 0, 0);
        }
        __syncthreads();
    }
    // epilogue: C/D layout col=lane&15, row=(lane>>4)*4+reg
    #pragma unroll
    for (int t = 0; t < 19; t++) {
        int col = t * 16 + lrow;
        float bv = bias[col];
        #pragma unroll
        for (int r = 0; r < 2; r++) {
            int rbase = bm + wv * 32 + r * 16 + quad * 4;
            #pragma unroll
            for (int g = 0; g < 4; g++) {
                int row = rbase + g;
                if (row < M) {
                    float v = fmaxf(acc[r][t][g] + bv, 0.f);
                    if (OUT8) {
                        v *= inv_out[row];   // pre-scale for next layer's gather
                        int p = __builtin_amdgcn_cvt_pk_fp8_f32(v, v, 0, false);
                        C8[(size_t)row * 304 + col] = (unsigned char)(p & 0xff);
                    } else {
                        C[(size_t)row * D_H + col] = (short)f2bf(v);
                    }
                }
            }
        }
    }
}

// ---------------- column max-pool over bf16 h (stride 152 dwords) ----------
__global__ void k_pool_bf(const unsigned* __restrict__ h, int* __restrict__ pooled) {
    int t = threadIdx.x;   // 256, active < 152
    if (t >= 152) return;
    int r0 = blockIdx.x * 256;
    int r1 = min(r0 + 256, TOTN);
    float m0 = 0.f, m1 = 0.f;   // relu outputs >= 0
    for (int r = r0; r < r1; r++) {
        unsigned u = h[(size_t)r * 152 + t];
        m0 = fmaxf(m0, __uint_as_float(u << 16));
        m1 = fmaxf(m1, __uint_as_float(u & 0xffff0000u));
    }
    atomicMax(&pooled[2 * t],     __float_as_int(m0));
    atomicMax(&pooled[2 * t + 1], __float_as_int(m1));
}

// ---------------- MLP head: 304 -> 128 -> 64 -> 1, sigmoid ----------------
__global__ void k_mlp(const int* __restrict__ pooled_i,
                      const float* __restrict__ fW1, const float* __restrict__ fb1,
                      const float* __restrict__ fW2, const float* __restrict__ fb2,
                      const float* __restrict__ fW3, const float* __restrict__ fb3,
                      float* __restrict__ out) {
    __shared__ float p[D_H];
    __shared__ float z1[128];
    __shared__ float z2[64];
    int t = threadIdx.x;  // 320
    if (t < D_H) p[t] = __int_as_float(pooled_i[t]);
    __syncthreads();
    if (t < 128) {
        float acc = fb1[t];
        for (int k = 0; k < D_H; k++) acc += p[k] * fW1[k * 128 + t];
        z1[t] = fmaxf(acc, 0.f);
    }
    __syncthreads();
    if (t < 64) {
        float acc = fb2[t];
        for (int k = 0; k < 128; k++) acc += z1[k] * fW2[k * 64 + t];
        z2[t] = fmaxf(acc, 0.f);
    }
    __syncthreads();
    if (t == 0) {
        float acc = fb3[0];
        for (int k = 0; k < 64; k++) acc += z2[k] * fW3[k];
        out[0] = 1.f / (1.f + expf(-acc));
    }
}

extern "C" void kernel_launch(void* const* d_in, const int* in_sizes, int n_in,
                              void* d_out, int out_size, void* d_ws, size_t ws_size,
                              hipStream_t stream) {
    const float* x1 = (const float*)d_in[0];
    const float* x2 = (const float*)d_in[1];
    const float* x3 = (const float*)d_in[2];
    const int* src1 = (const int*)d_in[3];
    const int* dst1 = (const int*)d_in[4];
    const int* src2 = (const int*)d_in[5];
    const int* dst2 = (const int*)d_in[6];
    const int* src3 = (const int*)d_in[7];
    const int* dst3 = (const int*)d_in[8];
    const float* W1 = (const float*)d_in[9];
    const float* b1 = (const float*)d_in[10];
    const float* W2 = (const float*)d_in[11];
    const float* b2 = (const float*)d_in[12];
    const float* W3 = (const float*)d_in[13];
    const float* b3 = (const float*)d_in[14];
    const float* fW1 = (const float*)d_in[15];
    const float* fb1 = (const float*)d_in[16];
    const float* fW2 = (const float*)d_in[17];
    const float* fb2 = (const float*)d_in[18];
    const float* fW3 = (const float*)d_in[19];
    const float* fb3 = (const float*)d_in[20];
    float* out = (float*)d_out;

    char* w = (char*)d_ws;
    unsigned* X8 = (unsigned*)w; w += (size_t)TOTN * 32 * 4;          // fp8 60000x128
    unsigned* Q8 = (unsigned*)w; w += (size_t)TOTN * 76 * 4;          // fp8 60000x304
    unsigned* P  = (unsigned*)w; w += (size_t)TOTN * 160 * 4;         // bf16 60000x320
    unsigned* Qb = (unsigned*)w; w += (size_t)TOTN * 152 * 4;         // bf16 60000x304
    short* Wt1   = (short*)w;    w += (size_t)D_H * 128 * 2;
    short* Wt2   = (short*)w;    w += (size_t)D_H * 320 * 2;
    short* Wt3   = (short*)w;    w += (size_t)D_H * 320 * 2;
    float* inv_out = (float*)w;  w += (size_t)TOTN * 4;
    float* inv_in  = (float*)w;  w += (size_t)TOTN * 4;
    int* out_cnt   = (int*)w;    w += (size_t)TOTN * 4;
    int* in_cnt    = (int*)w;    w += (size_t)TOTN * 4;
    int* row_ptr   = (int*)w;    w += (size_t)(TOTN + 4) * 4;
    int* cursor    = (int*)w;    w += (size_t)TOTN * 4;
    int* csr       = (int*)w;    w += (size_t)TOTE * 4;
    int* excl      = (int*)w;    w += (size_t)TOTN * 4;
    int* btot      = (int*)w;    w += 64 * 4;
    int* boff      = (int*)w;    w += 64 * 4;
    int* pooled    = (int*)w;    w += 320 * 4;

    hipMemsetAsync(out_cnt, 0, 2 * (size_t)TOTN * 4, stream);  // out_cnt + in_cnt
    hipMemsetAsync(pooled, 0, D_H * 4, stream);

    k_deg<<<(TOTE + 255) / 256, 256, 0, stream>>>(src1, dst1, src2, dst2, src3, dst3,
                                                  out_cnt, in_cnt);
    k_inv<<<(TOTN + 255) / 256, 256, 0, stream>>>(out_cnt, in_cnt, inv_out, inv_in);
    k_pack8<<<(3 * NODES * D_IN / 4 + 255) / 256, 256, 0, stream>>>(
        (const float4*)x1, (const float4*)x2, (const float4*)x3, inv_out, X8);
    k_scanA<<<SCAN_B, 1024, 0, stream>>>(in_cnt, excl, btot);
    k_scanB<<<1, 64, 0, stream>>>(btot, boff);
    k_scanC<<<SCAN_B, 1024, 0, stream>>>(excl, boff, row_ptr, cursor);
    k_fill<<<(TOTE + 255) / 256, 256, 0, stream>>>(src1, dst1, src2, dst2, src3, dst3,
                                                   cursor, csr);
    k_prepw<<<(D_H * 128 + 255) / 256, 256, 0, stream>>>(W1, Wt1, 128, 128);
    k_prepw<<<(D_H * 320 + 255) / 256, 256, 0, stream>>>(W2, Wt2, 304, 320);
    k_prepw<<<(D_H * 320 + 255) / 256, 256, 0, stream>>>(W3, Wt3, 304, 320);

    int ggrid = (TOTN + 127) / 128;  // 469

    // layer 1: X8(fp8*inv_out,128) -> SpMM -> P(bf16,128) -> GEMM(K=128) -> Q8
    k_spmm_f8<32, 64, 32><<<TOTN / 8, 256, 0, stream>>>(X8, P, row_ptr, csr, inv_in);
    k_gemm_mfma<true><<<ggrid, 256, 0, stream>>>((const short*)P, 128, Wt1, b1, inv_out,
                                                 nullptr, (unsigned char*)Q8, TOTN, 128);
    // layer 2
    k_spmm_f8<76, 160, 64><<<TOTN / 4, 256, 0, stream>>>(Q8, P, row_ptr, csr, inv_in);
    k_gemm_mfma<true><<<ggrid, 256, 0, stream>>>((const short*)P, 320, Wt2, b2, inv_out,
                                                 nullptr, (unsigned char*)Q8, TOTN, 320);
    // layer 3 -> bf16 Qb for pooling
    k_spmm_f8<76, 160, 64><<<TOTN / 4, 256, 0, stream>>>(Q8, P, row_ptr, csr, inv_in);
    k_gemm_mfma<false><<<ggrid, 256, 0, stream>>>((const short*)P, 320, Wt3, b3, nullptr,
                                                  (short*)Qb, nullptr, TOTN, 320);

    k_pool_bf<<<(TOTN + 255) / 256, 256, 0, stream>>>(Qb, pooled);
    k_mlp<<<1, 320, 0, stream>>>(pooled, fW1, fb1, fW2, fb2, fW3, fb3, out);
}

// Round 5
// 554.330 us; speedup vs baseline: 3.0257x; 1.1329x over previous
//
#include <hip/hip_runtime.h>
#include <hip/hip_bf16.h>
#include <math.h>

#define NODES 20000
#define EDGES 320000
#define NB 3
#define TOTN (NODES * NB)   // 60000
#define TOTE (EDGES * NB)   // 960000
#define D_IN 128
#define D_H 304
#define LDT 40              // LDS row stride (shorts) — breaks pow2 bank pattern
#define SCAN_B 59           // ceil(60000/1024)
#define SLICES 16
#define SLICE_E (EDGES / SLICES)   // 20000

typedef __attribute__((ext_vector_type(8))) short short8;
typedef __attribute__((ext_vector_type(4))) float f32x4;
typedef __attribute__((ext_vector_type(2))) float f32x2;

__device__ __forceinline__ unsigned short f2bf(float f) {
    unsigned u = __float_as_uint(f);
    unsigned r = (u + 0x7fffu + ((u >> 16) & 1u)) >> 16;   // RNE
    return (unsigned short)r;
}
__device__ __forceinline__ unsigned pack_bf2(float a, float b) {
    return (unsigned)f2bf(a) | ((unsigned)f2bf(b) << 16);
}

// ------- pack x1|x2|x3 fp32 -> X fp8 (60000 x 128), pre-scaled by inv_out -------
__global__ void k_pack8(const float4* __restrict__ x1, const float4* __restrict__ x2,
                        const float4* __restrict__ x3, const float* __restrict__ inv_out,
                        unsigned* __restrict__ q) {
    const int per = NODES * D_IN / 4;  // out dwords per graph (32 per row)
    int i = blockIdx.x * 256 + threadIdx.x;
    if (i >= 3 * per) return;
    const float4* s; int j;
    if (i < per)          { s = x1; j = i; }
    else if (i < 2 * per) { s = x2; j = i - per; }
    else                  { s = x3; j = i - 2 * per; }
    float4 v = s[j];
    float sc = inv_out[i >> 5];   // 32 dwords per row, global node id
    int p = __builtin_amdgcn_cvt_pk_fp8_f32(v.x * sc, v.y * sc, 0, false);
    p = __builtin_amdgcn_cvt_pk_fp8_f32(v.z * sc, v.w * sc, p, true);
    q[i] = (unsigned)p;
}

// ------- per-(graph,slice) LDS histograms: no global atomics -------
// blockIdx.x in [0,48): g = bx/SLICES, s = bx%SLICES; blockIdx.y: 0=in(dst), 1=out(src)
__global__ __launch_bounds__(256, 1) void k_hist(
    const int* __restrict__ s1, const int* __restrict__ d1,
    const int* __restrict__ s2, const int* __restrict__ d2,
    const int* __restrict__ s3, const int* __restrict__ d3,
    int* __restrict__ partial_in, int* __restrict__ partial_out) {
    __shared__ int hist[NODES];   // 80 KB
    int g = blockIdx.x / SLICES, s = blockIdx.x % SLICES;
    bool isOut = (blockIdx.y == 1);
    const int* ep;
    if (isOut) ep = (g == 0) ? s1 : ((g == 1) ? s2 : s3);
    else       ep = (g == 0) ? d1 : ((g == 1) ? d2 : d3);
    ep += s * SLICE_E;
    for (int i = threadIdx.x; i < NODES; i += 256) hist[i] = 0;
    __syncthreads();
    for (int i = threadIdx.x; i < SLICE_E; i += 256)
        atomicAdd(&hist[ep[i]], 1);
    __syncthreads();
    int* po = (isOut ? partial_out : partial_in) + (size_t)blockIdx.x * NODES;
    for (int i = threadIdx.x; i < NODES; i += 256) po[i] = hist[i];
}

// ------- sum slice partials -> in_cnt + fused inv_in / inv_out -------
__global__ void k_reduce(const int* __restrict__ partial_in,
                         const int* __restrict__ partial_out,
                         int* __restrict__ in_cnt,
                         float* __restrict__ inv_in, float* __restrict__ inv_out) {
    int n = blockIdx.x * 256 + threadIdx.x;
    if (n >= TOTN) return;
    int g = n / NODES, ln = n - g * NODES;
    const int* pi = partial_in + (size_t)g * SLICES * NODES + ln;
    const int* po = partial_out + (size_t)g * SLICES * NODES + ln;
    int ci = 0, co = 0;
    #pragma unroll
    for (int s = 0; s < SLICES; s++) { ci += pi[s * NODES]; co += po[s * NODES]; }
    in_cnt[n] = ci;
    inv_in[n]  = 1.0f / sqrtf((float)max(ci, 1));
    inv_out[n] = 1.0f / sqrtf((float)max(co, 1));
}

// ------- parallel scan: A (per-block excl + total), B (scan totals), C (apply) -------
__global__ void k_scanA(const int* __restrict__ cnt, int* __restrict__ excl,
                        int* __restrict__ btot) {
    __shared__ int wsum[16];
    int b = blockIdx.x, t = threadIdx.x;
    int i = b * 1024 + t;
    int lane = t & 63, wid = t >> 6;
    int v = (i < TOTN) ? cnt[i] : 0;
    int sv = v;
    #pragma unroll
    for (int o = 1; o < 64; o <<= 1) {
        int u = __shfl_up(sv, o, 64);
        if (lane >= o) sv += u;
    }
    if (lane == 63) wsum[wid] = sv;
    __syncthreads();
    if (t < 16) {
        int w = wsum[t];
        #pragma unroll
        for (int o = 1; o < 16; o <<= 1) {
            int u = __shfl_up(w, o, 16);
            if (t >= o) w += u;
        }
        wsum[t] = w;
    }
    __syncthreads();
    int wbase = (wid > 0) ? wsum[wid - 1] : 0;
    if (i < TOTN) excl[i] = wbase + sv - v;
    if (t == 0) btot[b] = wsum[15];
}

__global__ void k_scanB(const int* __restrict__ btot, int* __restrict__ boff) {
    int t = threadIdx.x;  // 64
    int v = (t < SCAN_B) ? btot[t] : 0;
    int sv = v;
    #pragma unroll
    for (int o = 1; o < 64; o <<= 1) {
        int u = __shfl_up(sv, o, 64);
        if (t >= o) sv += u;
    }
    if (t < SCAN_B) boff[t] = sv - v;  // exclusive
}

__global__ void k_scanC(const int* __restrict__ excl, const int* __restrict__ boff,
                        int* __restrict__ row_ptr) {
    int i = blockIdx.x * 1024 + threadIdx.x;
    if (i < TOTN) row_ptr[i] = excl[i] + boff[i >> 10];
    if (i == 0) row_ptr[TOTN] = TOTE;  // sum of in-degrees is exactly #edges
}

// ------- per-(slice,node) CSR base offsets: O = row_ptr + prefix over slices -------
__global__ void k_off(const int* __restrict__ partial_in, const int* __restrict__ row_ptr,
                      int* __restrict__ O) {
    int n = blockIdx.x * 256 + threadIdx.x;
    if (n >= TOTN) return;
    int g = n / NODES, ln = n - g * NODES;
    const int* pi = partial_in + (size_t)g * SLICES * NODES + ln;
    int* on = O + (size_t)g * SLICES * NODES + ln;
    int run = row_ptr[n];
    #pragma unroll
    for (int s = 0; s < SLICES; s++) {
        on[s * NODES] = run;
        run += pi[s * NODES];
    }
}

// ------- CSR fill via LDS cursors (global-atomic-free) -------
__global__ __launch_bounds__(256, 1) void k_fill2(
    const int* __restrict__ s1, const int* __restrict__ d1,
    const int* __restrict__ s2, const int* __restrict__ d2,
    const int* __restrict__ s3, const int* __restrict__ d3,
    const int* __restrict__ O, int* __restrict__ csr) {
    __shared__ int cur[NODES];   // 80 KB
    int g = blockIdx.x / SLICES, s = blockIdx.x % SLICES;
    const int* sp = (g == 0) ? s1 : ((g == 1) ? s2 : s3);
    const int* dp = (g == 0) ? d1 : ((g == 1) ? d2 : d3);
    sp += s * SLICE_E; dp += s * SLICE_E;
    const int* on = O + (size_t)blockIdx.x * NODES;
    for (int i = threadIdx.x; i < NODES; i += 256) cur[i] = on[i];
    __syncthreads();
    int base = g * NODES;
    for (int i = threadIdx.x; i < SLICE_E; i += 256) {
        int d = dp[i];
        int sv = sp[i] + base;
        int pos = atomicAdd(&cur[d], 1);
        csr[pos] = sv;
    }
}

// ------- SpMM gather, fp8 (pre-scaled by inv_out) -> bf16, fp32 accum, unroll x4 ----
template <int IND, int OUTLD, int LANES>
__global__ void k_spmm_f8(const unsigned* __restrict__ h, unsigned* __restrict__ agg,
                          const int* __restrict__ row_ptr, const int* __restrict__ csr,
                          const float* __restrict__ inv_in) {
    constexpr int CH = (IND + LANES - 1) / LANES;
    constexpr int NPB = 256 / LANES;
    int n = blockIdx.x * NPB + (threadIdx.x / LANES);
    int lane = threadIdx.x % LANES;
    f32x2 acc[CH][2];
    #pragma unroll
    for (int c = 0; c < CH; c++) {
        acc[c][0] = (f32x2){0.f, 0.f};
        acc[c][1] = (f32x2){0.f, 0.f};
    }
    int k0 = row_ptr[n], k1 = row_ptr[n + 1];
    int k = k0;
    for (; k + 4 <= k1; k += 4) {
        int s0 = csr[k], s1 = csr[k + 1], s2 = csr[k + 2], s3 = csr[k + 3];
        const unsigned* r0 = h + (size_t)s0 * IND;
        const unsigned* r1 = h + (size_t)s1 * IND;
        const unsigned* r2 = h + (size_t)s2 * IND;
        const unsigned* r3 = h + (size_t)s3 * IND;
        #pragma unroll
        for (int c = 0; c < CH; c++) {
            int idx = c * LANES + lane;
            if (idx < IND) {
                unsigned u0 = r0[idx], u1 = r1[idx], u2 = r2[idx], u3 = r3[idx];
                f32x2 lo = __builtin_amdgcn_cvt_pk_f32_fp8(u0, false)
                         + __builtin_amdgcn_cvt_pk_f32_fp8(u1, false)
                         + __builtin_amdgcn_cvt_pk_f32_fp8(u2, false)
                         + __builtin_amdgcn_cvt_pk_f32_fp8(u3, false);
                f32x2 hi = __builtin_amdgcn_cvt_pk_f32_fp8(u0, true)
                         + __builtin_amdgcn_cvt_pk_f32_fp8(u1, true)
                         + __builtin_amdgcn_cvt_pk_f32_fp8(u2, true)
                         + __builtin_amdgcn_cvt_pk_f32_fp8(u3, true);
                acc[c][0] += lo;
                acc[c][1] += hi;
            }
        }
    }
    for (; k < k1; k++) {
        int s0 = csr[k];
        const unsigned* r0 = h + (size_t)s0 * IND;
        #pragma unroll
        for (int c = 0; c < CH; c++) {
            int idx = c * LANES + lane;
            if (idx < IND) {
                unsigned u0 = r0[idx];
                acc[c][0] += __builtin_amdgcn_cvt_pk_f32_fp8(u0, false);
                acc[c][1] += __builtin_amdgcn_cvt_pk_f32_fp8(u0, true);
            }
        }
    }
    float wi = inv_in[n];
    unsigned* ar = agg + (size_t)n * OUTLD;
    #pragma unroll
    for (int c = 0; c < CH; c++) {
        int idx = c * LANES + lane;
        if (idx < IND) {
            uint2 st;
            st.x = pack_bf2(acc[c][0][0] * wi, acc[c][0][1] * wi);
            st.y = pack_bf2(acc[c][1][0] * wi, acc[c][1][1] * wi);
            *(uint2*)(&ar[2 * idx]) = st;
        }
    }
    for (int idx = 2 * IND + lane; idx < OUTLD; idx += LANES) ar[idx] = 0;  // zero pad
}

// ------- W prep: fp32 W[K][304] -> bf16 Wt[304][Kpad] (zero-padded K) -------
__global__ void k_prepw(const float* __restrict__ W, short* __restrict__ Wt,
                        int K, int Kpad) {
    int id = blockIdx.x * 256 + threadIdx.x;
    if (id >= D_H * Kpad) return;
    int n = id / Kpad, k = id - n * Kpad;
    short v = 0;
    if (k < K) v = (short)f2bf(W[k * D_H + n]);
    Wt[id] = v;
}

// ------- bf16 MFMA GEMM: relu(A[MxK] @ Wt^T + bias) -> fp8 (x inv_out) or bf16 ----
template <bool OUT8>
__global__ __launch_bounds__(256, 2) void k_gemm_mfma(
    const short* __restrict__ A, int lda,
    const short* __restrict__ Wt,
    const float* __restrict__ bias,
    const float* __restrict__ inv_out,
    short* __restrict__ C, unsigned char* __restrict__ C8, int M, int K) {
    __shared__ short As[128 * LDT];
    __shared__ short Bs[304 * LDT];
    int tid = threadIdx.x;
    int wv = tid >> 6, lane = tid & 63;
    int quad = lane >> 4, lrow = lane & 15;
    int bm = blockIdx.x * 128;

    f32x4 acc[2][19];
    #pragma unroll
    for (int r = 0; r < 2; r++)
        #pragma unroll
        for (int t = 0; t < 19; t++) acc[r][t] = (f32x4){0.f, 0.f, 0.f, 0.f};

    for (int kt = 0; kt < K; kt += 32) {
        #pragma unroll
        for (int j = 0; j < 2; j++) {
            int q = j * 256 + tid;
            int row = q >> 2, off = q & 3;
            int grow = bm + row;
            uint4 v = make_uint4(0u, 0u, 0u, 0u);
            if (grow < M) v = *(const uint4*)(A + (size_t)grow * lda + kt + off * 8);
            *(uint4*)(&As[row * LDT + off * 8]) = v;
        }
        for (int q = tid; q < 1216; q += 256) {
            int n = q >> 2, off = q & 3;
            uint4 v = *(const uint4*)(Wt + (size_t)n * K + kt + off * 8);
            *(uint4*)(&Bs[n * LDT + off * 8]) = v;
        }
        __syncthreads();
        short8 a0 = *(const short8*)(&As[(wv * 32 + lrow) * LDT + quad * 8]);
        short8 a1 = *(const short8*)(&As[(wv * 32 + 16 + lrow) * LDT + quad * 8]);
        #pragma unroll
        for (int t = 0; t < 19; t++) {
            short8 b = *(const short8*)(&Bs[(t * 16 + lrow) * LDT + quad * 8]);
            acc[0][t] = __builtin_amdgcn_mfma_f32_16x16x32_bf16(a0, b, acc[0][t], 0, 0, 0);
            acc[1][t] = __builtin_amdgcn_mfma_f32_16x16x32_bf16(a1, b, acc[1][t], 0, 0, 0);
        }
        __syncthreads();
    }
    // epilogue: C/D layout col=lane&15, row=(lane>>4)*4+reg
    #pragma unroll
    for (int t = 0; t < 19; t++) {
        int col = t * 16 + lrow;
        float bv = bias[col];
        #pragma unroll
        for (int r = 0; r < 2; r++) {
            int rbase = bm + wv * 32 + r * 16 + quad * 4;
            #pragma unroll
            for (int g = 0; g < 4; g++) {
                int row = rbase + g;
                if (row < M) {
                    float v = fmaxf(acc[r][t][g] + bv, 0.f);
                    if (OUT8) {
                        v *= inv_out[row];   // pre-scale for next layer's gather
                        int p = __builtin_amdgcn_cvt_pk_fp8_f32(v, v, 0, false);
                        C8[(size_t)row * 304 + col] = (unsigned char)(p & 0xff);
                    } else {
                        C[(size_t)row * D_H + col] = (short)f2bf(v);
                    }
                }
            }
        }
    }
}

// ---------------- column max-pool over bf16 h (stride 152 dwords) ----------
__global__ void k_pool_bf(const unsigned* __restrict__ h, int* __restrict__ pooled) {
    int t = threadIdx.x;   // 256, active < 152
    if (t >= 152) return;
    int r0 = blockIdx.x * 256;
    int r1 = min(r0 + 256, TOTN);
    float m0 = 0.f, m1 = 0.f;   // relu outputs >= 0
    for (int r = r0; r < r1; r++) {
        unsigned u = h[(size_t)r * 152 + t];
        m0 = fmaxf(m0, __uint_as_float(u << 16));
        m1 = fmaxf(m1, __uint_as_float(u & 0xffff0000u));
    }
    atomicMax(&pooled[2 * t],     __float_as_int(m0));
    atomicMax(&pooled[2 * t + 1], __float_as_int(m1));
}

// ---------------- MLP head: 304 -> 128 -> 64 -> 1, sigmoid ----------------
__global__ void k_mlp(const int* __restrict__ pooled_i,
                      const float* __restrict__ fW1, const float* __restrict__ fb1,
                      const float* __restrict__ fW2, const float* __restrict__ fb2,
                      const float* __restrict__ fW3, const float* __restrict__ fb3,
                      float* __restrict__ out) {
    __shared__ float p[D_H];
    __shared__ float z1[128];
    __shared__ float z2[64];
    int t = threadIdx.x;  // 320
    if (t < D_H) p[t] = __int_as_float(pooled_i[t]);
    __syncthreads();
    if (t < 128) {
        float acc = fb1[t];
        for (int k = 0; k < D_H; k++) acc += p[k] * fW1[k * 128 + t];
        z1[t] = fmaxf(acc, 0.f);
    }
    __syncthreads();
    if (t < 64) {
        float acc = fb2[t];
        for (int k = 0; k < 128; k++) acc += z1[k] * fW2[k * 64 + t];
        z2[t] = fmaxf(acc, 0.f);
    }
    __syncthreads();
    if (t == 0) {
        float acc = fb3[0];
        for (int k = 0; k < 64; k++) acc += z2[k] * fW3[k];
        out[0] = 1.f / (1.f + expf(-acc));
    }
}

extern "C" void kernel_launch(void* const* d_in, const int* in_sizes, int n_in,
                              void* d_out, int out_size, void* d_ws, size_t ws_size,
                              hipStream_t stream) {
    const float* x1 = (const float*)d_in[0];
    const float* x2 = (const float*)d_in[1];
    const float* x3 = (const float*)d_in[2];
    const int* src1 = (const int*)d_in[3];
    const int* dst1 = (const int*)d_in[4];
    const int* src2 = (const int*)d_in[5];
    const int* dst2 = (const int*)d_in[6];
    const int* src3 = (const int*)d_in[7];
    const int* dst3 = (const int*)d_in[8];
    const float* W1 = (const float*)d_in[9];
    const float* b1 = (const float*)d_in[10];
    const float* W2 = (const float*)d_in[11];
    const float* b2 = (const float*)d_in[12];
    const float* W3 = (const float*)d_in[13];
    const float* b3 = (const float*)d_in[14];
    const float* fW1 = (const float*)d_in[15];
    const float* fb1 = (const float*)d_in[16];
    const float* fW2 = (const float*)d_in[17];
    const float* fb2 = (const float*)d_in[18];
    const float* fW3 = (const float*)d_in[19];
    const float* fb3 = (const float*)d_in[20];
    float* out = (float*)d_out;

    char* w = (char*)d_ws;
    unsigned* X8 = (unsigned*)w; w += (size_t)TOTN * 32 * 4;          // fp8 60000x128
    unsigned* Q8 = (unsigned*)w; w += (size_t)TOTN * 76 * 4;          // fp8 60000x304
    unsigned* P  = (unsigned*)w; w += (size_t)TOTN * 160 * 4;         // bf16 60000x320
    unsigned* Qb = (unsigned*)w; w += (size_t)TOTN * 152 * 4;         // bf16 60000x304
    short* Wt1   = (short*)w;    w += (size_t)D_H * 128 * 2;
    short* Wt2   = (short*)w;    w += (size_t)D_H * 320 * 2;
    short* Wt3   = (short*)w;    w += (size_t)D_H * 320 * 2;
    int* partial_in  = (int*)w;  w += (size_t)NB * SLICES * NODES * 4;  // 3.84 MB
    int* partial_out = (int*)w;  w += (size_t)NB * SLICES * NODES * 4;
    int* O           = (int*)w;  w += (size_t)NB * SLICES * NODES * 4;
    float* inv_out = (float*)w;  w += (size_t)TOTN * 4;
    float* inv_in  = (float*)w;  w += (size_t)TOTN * 4;
    int* in_cnt    = (int*)w;    w += (size_t)TOTN * 4;
    int* row_ptr   = (int*)w;    w += (size_t)(TOTN + 4) * 4;
    int* csr       = (int*)w;    w += (size_t)TOTE * 4;
    int* excl      = (int*)w;    w += (size_t)TOTN * 4;
    int* btot      = (int*)w;    w += 64 * 4;
    int* boff      = (int*)w;    w += 64 * 4;
    int* pooled    = (int*)w;    w += 320 * 4;

    hipMemsetAsync(pooled, 0, D_H * 4, stream);

    k_hist<<<dim3(NB * SLICES, 2), 256, 0, stream>>>(src1, dst1, src2, dst2, src3, dst3,
                                                     partial_in, partial_out);
    k_reduce<<<(TOTN + 255) / 256, 256, 0, stream>>>(partial_in, partial_out,
                                                     in_cnt, inv_in, inv_out);
    k_pack8<<<(3 * NODES * D_IN / 4 + 255) / 256, 256, 0, stream>>>(
        (const float4*)x1, (const float4*)x2, (const float4*)x3, inv_out, X8);
    k_scanA<<<SCAN_B, 1024, 0, stream>>>(in_cnt, excl, btot);
    k_scanB<<<1, 64, 0, stream>>>(btot, boff);
    k_scanC<<<SCAN_B, 1024, 0, stream>>>(excl, boff, row_ptr);
    k_off<<<(TOTN + 255) / 256, 256, 0, stream>>>(partial_in, row_ptr, O);
    k_fill2<<<NB * SLICES, 256, 0, stream>>>(src1, dst1, src2, dst2, src3, dst3, O, csr);
    k_prepw<<<(D_H * 128 + 255) / 256, 256, 0, stream>>>(W1, Wt1, 128, 128);
    k_prepw<<<(D_H * 320 + 255) / 256, 256, 0, stream>>>(W2, Wt2, 304, 320);
    k_prepw<<<(D_H * 320 + 255) / 256, 256, 0, stream>>>(W3, Wt3, 304, 320);

    int ggrid = (TOTN + 127) / 128;  // 469

    // layer 1: X8(fp8*inv_out,128) -> SpMM -> P(bf16,128) -> GEMM(K=128) -> Q8
    k_spmm_f8<32, 64, 32><<<TOTN / 8, 256, 0, stream>>>(X8, P, row_ptr, csr, inv_in);
    k_gemm_mfma<true><<<ggrid, 256, 0, stream>>>((const short*)P, 128, Wt1, b1, inv_out,
                                                 nullptr, (unsigned char*)Q8, TOTN, 128);
    // layer 2
    k_spmm_f8<76, 160, 64><<<TOTN / 4, 256, 0, stream>>>(Q8, P, row_ptr, csr, inv_in);
    k_gemm_mfma<true><<<ggrid, 256, 0, stream>>>((const short*)P, 320, Wt2, b2, inv_out,
                                                 nullptr, (unsigned char*)Q8, TOTN, 320);
    // layer 3 -> bf16 Qb for pooling
    k_spmm_f8<76, 160, 64><<<TOTN / 4, 256, 0, stream>>>(Q8, P, row_ptr, csr, inv_in);
    k_gemm_mfma<false><<<ggrid, 256, 0, stream>>>((const short*)P, 320, Wt3, b3, nullptr,
                                                  (short*)Qb, nullptr, TOTN, 320);

    k_pool_bf<<<(TOTN + 255) / 256, 256, 0, stream>>>(Qb, pooled);
    k_mlp<<<1, 320, 0, stream>>>(pooled, fW1, fb1, fW2, fb2, fW3, fb3, out);
}

// Round 6
// 449.296 us; speedup vs baseline: 3.7331x; 1.2338x over previous
//
#include <hip/hip_runtime.h>
#include <hip/hip_bf16.h>
#include <math.h>

#define NODES 20000
#define EDGES 320000
#define NB 3
#define TOTN (NODES * NB)   // 60000
#define TOTE (EDGES * NB)   // 960000
#define D_IN 128
#define D_H 304
#define LDT 40              // LDS row stride (shorts) — breaks pow2 bank pattern
#define SCAN_B 59           // ceil(60000/1024)
#define SLICES 32
#define SLICE_E (EDGES / SLICES)   // 10000

typedef __attribute__((ext_vector_type(8))) short short8;
typedef __attribute__((ext_vector_type(4))) float f32x4;
typedef __attribute__((ext_vector_type(2))) float f32x2;

__device__ __forceinline__ unsigned short f2bf(float f) {
    unsigned u = __float_as_uint(f);
    unsigned r = (u + 0x7fffu + ((u >> 16) & 1u)) >> 16;   // RNE
    return (unsigned short)r;
}
__device__ __forceinline__ unsigned pack_bf2(float a, float b) {
    return (unsigned)f2bf(a) | ((unsigned)f2bf(b) << 16);
}

// ------- pack x1|x2|x3 fp32 -> X fp8 (60000 x 128), pre-scaled by inv_out -------
__global__ void k_pack8(const float4* __restrict__ x1, const float4* __restrict__ x2,
                        const float4* __restrict__ x3, const float* __restrict__ inv_out,
                        unsigned* __restrict__ q) {
    const int per = NODES * D_IN / 4;  // out dwords per graph (32 per row)
    int i = blockIdx.x * 256 + threadIdx.x;
    if (i >= 3 * per) return;
    const float4* s; int j;
    if (i < per)          { s = x1; j = i; }
    else if (i < 2 * per) { s = x2; j = i - per; }
    else                  { s = x3; j = i - 2 * per; }
    float4 v = s[j];
    float sc = inv_out[i >> 5];   // 32 dwords per row, global node id
    int p = __builtin_amdgcn_cvt_pk_fp8_f32(v.x * sc, v.y * sc, 0, false);
    p = __builtin_amdgcn_cvt_pk_fp8_f32(v.z * sc, v.w * sc, p, true);
    q[i] = (unsigned)p;
}

// ------- per-(graph,slice) LDS histograms: no global atomics -------
// blockIdx.x in [0,96): g = bx/SLICES, s = bx%SLICES; blockIdx.y: 0=in(dst), 1=out(src)
__global__ __launch_bounds__(256, 1) void k_hist(
    const int* __restrict__ s1, const int* __restrict__ d1,
    const int* __restrict__ s2, const int* __restrict__ d2,
    const int* __restrict__ s3, const int* __restrict__ d3,
    int* __restrict__ partial_in, int* __restrict__ partial_out) {
    __shared__ int hist[NODES];   // 80 KB
    int g = blockIdx.x / SLICES, s = blockIdx.x % SLICES;
    bool isOut = (blockIdx.y == 1);
    const int* ep;
    if (isOut) ep = (g == 0) ? s1 : ((g == 1) ? s2 : s3);
    else       ep = (g == 0) ? d1 : ((g == 1) ? d2 : d3);
    ep += s * SLICE_E;
    for (int i = threadIdx.x; i < NODES; i += 256) hist[i] = 0;
    __syncthreads();
    for (int i = threadIdx.x; i < SLICE_E; i += 256)
        atomicAdd(&hist[ep[i]], 1);
    __syncthreads();
    int* po = (isOut ? partial_out : partial_in) + (size_t)blockIdx.x * NODES;
    for (int i = threadIdx.x; i < NODES; i += 256) po[i] = hist[i];
}

// ------- degrees from partials + inv factors + block-level scan (fused) -------
__global__ void k_degscan(const int* __restrict__ partial_in,
                          const int* __restrict__ partial_out,
                          float* __restrict__ inv_in, float* __restrict__ inv_out,
                          int* __restrict__ excl, int* __restrict__ btot) {
    __shared__ int wsum[16];
    int b = blockIdx.x, t = threadIdx.x;
    int i = b * 1024 + t;
    int lane = t & 63, wid = t >> 6;
    int v = 0;
    if (i < TOTN) {
        int g = i / NODES, ln = i - g * NODES;
        const int* pi = partial_in + (size_t)g * SLICES * NODES + ln;
        const int* po = partial_out + (size_t)g * SLICES * NODES + ln;
        int ci = 0, co = 0;
        #pragma unroll
        for (int s = 0; s < SLICES; s++) { ci += pi[s * NODES]; co += po[s * NODES]; }
        v = ci;
        inv_in[i]  = 1.0f / sqrtf((float)max(ci, 1));
        inv_out[i] = 1.0f / sqrtf((float)max(co, 1));
    }
    int sv = v;
    #pragma unroll
    for (int o = 1; o < 64; o <<= 1) {
        int u = __shfl_up(sv, o, 64);
        if (lane >= o) sv += u;
    }
    if (lane == 63) wsum[wid] = sv;
    __syncthreads();
    if (t < 16) {
        int w = wsum[t];
        #pragma unroll
        for (int o = 1; o < 16; o <<= 1) {
            int u = __shfl_up(w, o, 16);
            if (t >= o) w += u;
        }
        wsum[t] = w;
    }
    __syncthreads();
    int wbase = (wid > 0) ? wsum[wid - 1] : 0;
    if (i < TOTN) excl[i] = wbase + sv - v;
    if (t == 0) btot[b] = wsum[15];
}

__global__ void k_scanB(const int* __restrict__ btot, int* __restrict__ boff) {
    int t = threadIdx.x;  // 64
    int v = (t < SCAN_B) ? btot[t] : 0;
    int sv = v;
    #pragma unroll
    for (int o = 1; o < 64; o <<= 1) {
        int u = __shfl_up(sv, o, 64);
        if (t >= o) sv += u;
    }
    if (t < SCAN_B) boff[t] = sv - v;  // exclusive
}

// ------- row_ptr apply + per-(slice,node) CSR base offsets (fused) -------
__global__ void k_offC(const int* __restrict__ excl, const int* __restrict__ boff,
                       const int* __restrict__ partial_in,
                       int* __restrict__ row_ptr, int* __restrict__ O) {
    int n = blockIdx.x * 256 + threadIdx.x;
    if (n >= TOTN) {
        if (n == TOTN) row_ptr[TOTN] = TOTE;
        return;
    }
    if (n == 0) row_ptr[TOTN] = TOTE;
    int rp = excl[n] + boff[n >> 10];
    row_ptr[n] = rp;
    int g = n / NODES, ln = n - g * NODES;
    const int* pi = partial_in + (size_t)g * SLICES * NODES + ln;
    int* on = O + (size_t)g * SLICES * NODES + ln;
    int run = rp;
    #pragma unroll
    for (int s = 0; s < SLICES; s++) {
        on[s * NODES] = run;
        run += pi[s * NODES];
    }
}

// ------- CSR fill via LDS cursors (global-atomic-free) -------
__global__ __launch_bounds__(256, 1) void k_fill2(
    const int* __restrict__ s1, const int* __restrict__ d1,
    const int* __restrict__ s2, const int* __restrict__ d2,
    const int* __restrict__ s3, const int* __restrict__ d3,
    const int* __restrict__ O, int* __restrict__ csr) {
    __shared__ int cur[NODES];   // 80 KB
    int g = blockIdx.x / SLICES, s = blockIdx.x % SLICES;
    const int* sp = (g == 0) ? s1 : ((g == 1) ? s2 : s3);
    const int* dp = (g == 0) ? d1 : ((g == 1) ? d2 : d3);
    sp += s * SLICE_E; dp += s * SLICE_E;
    const int* on = O + (size_t)blockIdx.x * NODES;
    for (int i = threadIdx.x; i < NODES; i += 256) cur[i] = on[i];
    __syncthreads();
    int base = g * NODES;
    for (int i = threadIdx.x; i < SLICE_E; i += 256) {
        int d = dp[i];
        int sv = sp[i] + base;
        int pos = atomicAdd(&cur[d], 1);
        csr[pos] = sv;
    }
}

// ------- SpMM gather, fp8 (pre-scaled by inv_out) -> bf16, fp32 accum, unroll x8 ----
template <int IND, int OUTLD, int LANES>
__global__ void k_spmm_f8(const unsigned* __restrict__ h, unsigned* __restrict__ agg,
                          const int* __restrict__ row_ptr, const int* __restrict__ csr,
                          const float* __restrict__ inv_in) {
    constexpr int CH = (IND + LANES - 1) / LANES;
    constexpr int NPB = 256 / LANES;
    int n = blockIdx.x * NPB + (threadIdx.x / LANES);
    int lane = threadIdx.x % LANES;
    f32x2 acc[CH][2];
    #pragma unroll
    for (int c = 0; c < CH; c++) {
        acc[c][0] = (f32x2){0.f, 0.f};
        acc[c][1] = (f32x2){0.f, 0.f};
    }
    int k0 = row_ptr[n], k1 = row_ptr[n + 1];
    int k = k0;
    for (; k + 8 <= k1; k += 8) {
        const unsigned* r[8];
        #pragma unroll
        for (int e = 0; e < 8; e++) r[e] = h + (size_t)csr[k + e] * IND;
        #pragma unroll
        for (int c = 0; c < CH; c++) {
            int idx = c * LANES + lane;
            if (idx < IND) {
                unsigned u[8];
                #pragma unroll
                for (int e = 0; e < 8; e++) u[e] = r[e][idx];
                f32x2 lo = (f32x2){0.f, 0.f}, hi = (f32x2){0.f, 0.f};
                #pragma unroll
                for (int e = 0; e < 8; e++) {
                    lo += __builtin_amdgcn_cvt_pk_f32_fp8(u[e], false);
                    hi += __builtin_amdgcn_cvt_pk_f32_fp8(u[e], true);
                }
                acc[c][0] += lo;
                acc[c][1] += hi;
            }
        }
    }
    for (; k + 4 <= k1; k += 4) {
        const unsigned* r[4];
        #pragma unroll
        for (int e = 0; e < 4; e++) r[e] = h + (size_t)csr[k + e] * IND;
        #pragma unroll
        for (int c = 0; c < CH; c++) {
            int idx = c * LANES + lane;
            if (idx < IND) {
                #pragma unroll
                for (int e = 0; e < 4; e++) {
                    unsigned u = r[e][idx];
                    acc[c][0] += __builtin_amdgcn_cvt_pk_f32_fp8(u, false);
                    acc[c][1] += __builtin_amdgcn_cvt_pk_f32_fp8(u, true);
                }
            }
        }
    }
    for (; k < k1; k++) {
        const unsigned* r0 = h + (size_t)csr[k] * IND;
        #pragma unroll
        for (int c = 0; c < CH; c++) {
            int idx = c * LANES + lane;
            if (idx < IND) {
                unsigned u0 = r0[idx];
                acc[c][0] += __builtin_amdgcn_cvt_pk_f32_fp8(u0, false);
                acc[c][1] += __builtin_amdgcn_cvt_pk_f32_fp8(u0, true);
            }
        }
    }
    float wi = inv_in[n];
    unsigned* ar = agg + (size_t)n * OUTLD;
    #pragma unroll
    for (int c = 0; c < CH; c++) {
        int idx = c * LANES + lane;
        if (idx < IND) {
            uint2 st;
            st.x = pack_bf2(acc[c][0][0] * wi, acc[c][0][1] * wi);
            st.y = pack_bf2(acc[c][1][0] * wi, acc[c][1][1] * wi);
            *(uint2*)(&ar[2 * idx]) = st;
        }
    }
    for (int idx = 2 * IND + lane; idx < OUTLD; idx += LANES) ar[idx] = 0;  // zero pad
}

// ------- W prep: fp32 W[K][304] -> bf16 Wt[304][Kpad] (zero-padded K) -------
__global__ void k_prepw(const float* __restrict__ W, short* __restrict__ Wt,
                        int K, int Kpad) {
    int id = blockIdx.x * 256 + threadIdx.x;
    if (id >= D_H * Kpad) return;
    int n = id / Kpad, k = id - n * Kpad;
    short v = 0;
    if (k < K) v = (short)f2bf(W[k * D_H + n]);
    Wt[id] = v;
}

// ------- bf16 MFMA GEMM: relu(A[MxK] @ Wt^T + bias) ----------------------------
// MODE 0: store fp8 (x inv_out) to C8.  MODE 1: column max-pool -> atomicMax gpool.
template <int MODE>
__global__ __launch_bounds__(256, 2) void k_gemm_mfma(
    const short* __restrict__ A, int lda,
    const short* __restrict__ Wt,
    const float* __restrict__ bias,
    const float* __restrict__ inv_out,
    unsigned char* __restrict__ C8, int* __restrict__ gpool, int M, int K) {
    __shared__ short As[128 * LDT];
    __shared__ short Bs[304 * LDT];
    __shared__ int pmax[D_H];
    int tid = threadIdx.x;
    int wv = tid >> 6, lane = tid & 63;
    int quad = lane >> 4, lrow = lane & 15;
    int bm = blockIdx.x * 128;

    if (MODE == 1) {
        for (int i = tid; i < D_H; i += 256) pmax[i] = 0;
    }

    f32x4 acc[2][19];
    #pragma unroll
    for (int r = 0; r < 2; r++)
        #pragma unroll
        for (int t = 0; t < 19; t++) acc[r][t] = (f32x4){0.f, 0.f, 0.f, 0.f};

    for (int kt = 0; kt < K; kt += 32) {
        #pragma unroll
        for (int j = 0; j < 2; j++) {
            int q = j * 256 + tid;
            int row = q >> 2, off = q & 3;
            int grow = bm + row;
            uint4 v = make_uint4(0u, 0u, 0u, 0u);
            if (grow < M) v = *(const uint4*)(A + (size_t)grow * lda + kt + off * 8);
            *(uint4*)(&As[row * LDT + off * 8]) = v;
        }
        for (int q = tid; q < 1216; q += 256) {
            int n = q >> 2, off = q & 3;
            uint4 v = *(const uint4*)(Wt + (size_t)n * K + kt + off * 8);
            *(uint4*)(&Bs[n * LDT + off * 8]) = v;
        }
        __syncthreads();
        short8 a0 = *(const short8*)(&As[(wv * 32 + lrow) * LDT + quad * 8]);
        short8 a1 = *(const short8*)(&As[(wv * 32 + 16 + lrow) * LDT + quad * 8]);
        #pragma unroll
        for (int t = 0; t < 19; t++) {
            short8 b = *(const short8*)(&Bs[(t * 16 + lrow) * LDT + quad * 8]);
            acc[0][t] = __builtin_amdgcn_mfma_f32_16x16x32_bf16(a0, b, acc[0][t], 0, 0, 0);
            acc[1][t] = __builtin_amdgcn_mfma_f32_16x16x32_bf16(a1, b, acc[1][t], 0, 0, 0);
        }
        __syncthreads();
    }
    // epilogue: C/D layout col=lane&15, row=(lane>>4)*4+reg
    #pragma unroll
    for (int t = 0; t < 19; t++) {
        int col = t * 16 + lrow;
        float bv = bias[col];
        float m = 0.f;
        #pragma unroll
        for (int r = 0; r < 2; r++) {
            int rbase = bm + wv * 32 + r * 16 + quad * 4;
            #pragma unroll
            for (int g = 0; g < 4; g++) {
                int row = rbase + g;
                if (row < M) {
                    float v = fmaxf(acc[r][t][g] + bv, 0.f);
                    if (MODE == 0) {
                        v *= inv_out[row];   // pre-scale for next layer's gather
                        int p = __builtin_amdgcn_cvt_pk_fp8_f32(v, v, 0, false);
                        C8[(size_t)row * 304 + col] = (unsigned char)(p & 0xff);
                    } else {
                        m = fmaxf(m, v);
                    }
                }
            }
        }
        if (MODE == 1) atomicMax(&pmax[col], __float_as_int(m));
    }
    if (MODE == 1) {
        __syncthreads();
        for (int i = tid; i < D_H; i += 256)
            atomicMax(&gpool[i], pmax[i]);
    }
}

// ---------------- MLP head: 304 -> 128 -> 64 -> 1, sigmoid ----------------
__global__ void k_mlp(const int* __restrict__ pooled_i,
                      const float* __restrict__ fW1, const float* __restrict__ fb1,
                      const float* __restrict__ fW2, const float* __restrict__ fb2,
                      const float* __restrict__ fW3, const float* __restrict__ fb3,
                      float* __restrict__ out) {
    __shared__ float p[D_H];
    __shared__ float z1[128];
    __shared__ float z2[64];
    int t = threadIdx.x;  // 320
    if (t < D_H) p[t] = __int_as_float(pooled_i[t]);
    __syncthreads();
    if (t < 128) {
        float acc = fb1[t];
        for (int k = 0; k < D_H; k++) acc += p[k] * fW1[k * 128 + t];
        z1[t] = fmaxf(acc, 0.f);
    }
    __syncthreads();
    if (t < 64) {
        float acc = fb2[t];
        for (int k = 0; k < 128; k++) acc += z1[k] * fW2[k * 64 + t];
        z2[t] = fmaxf(acc, 0.f);
    }
    __syncthreads();
    if (t == 0) {
        float acc = fb3[0];
        for (int k = 0; k < 64; k++) acc += z2[k] * fW3[k];
        out[0] = 1.f / (1.f + expf(-acc));
    }
}

extern "C" void kernel_launch(void* const* d_in, const int* in_sizes, int n_in,
                              void* d_out, int out_size, void* d_ws, size_t ws_size,
                              hipStream_t stream) {
    const float* x1 = (const float*)d_in[0];
    const float* x2 = (const float*)d_in[1];
    const float* x3 = (const float*)d_in[2];
    const int* src1 = (const int*)d_in[3];
    const int* dst1 = (const int*)d_in[4];
    const int* src2 = (const int*)d_in[5];
    const int* dst2 = (const int*)d_in[6];
    const int* src3 = (const int*)d_in[7];
    const int* dst3 = (const int*)d_in[8];
    const float* W1 = (const float*)d_in[9];
    const float* b1 = (const float*)d_in[10];
    const float* W2 = (const float*)d_in[11];
    const float* b2 = (const float*)d_in[12];
    const float* W3 = (const float*)d_in[13];
    const float* b3 = (const float*)d_in[14];
    const float* fW1 = (const float*)d_in[15];
    const float* fb1 = (const float*)d_in[16];
    const float* fW2 = (const float*)d_in[17];
    const float* fb2 = (const float*)d_in[18];
    const float* fW3 = (const float*)d_in[19];
    const float* fb3 = (const float*)d_in[20];
    float* out = (float*)d_out;

    char* w = (char*)d_ws;
    unsigned* X8 = (unsigned*)w; w += (size_t)TOTN * 32 * 4;          // fp8 60000x128
    unsigned* Q8 = (unsigned*)w; w += (size_t)TOTN * 76 * 4;          // fp8 60000x304
    unsigned* P  = (unsigned*)w; w += (size_t)TOTN * 160 * 4;         // bf16 60000x320
    short* Wt1   = (short*)w;    w += (size_t)D_H * 128 * 2;
    short* Wt2   = (short*)w;    w += (size_t)D_H * 320 * 2;
    short* Wt3   = (short*)w;    w += (size_t)D_H * 320 * 2;
    int* partial_in  = (int*)w;  w += (size_t)NB * SLICES * NODES * 4;  // 7.68 MB
    int* partial_out = (int*)w;  w += (size_t)NB * SLICES * NODES * 4;
    int* O           = (int*)w;  w += (size_t)NB * SLICES * NODES * 4;
    float* inv_out = (float*)w;  w += (size_t)TOTN * 4;
    float* inv_in  = (float*)w;  w += (size_t)TOTN * 4;
    int* row_ptr   = (int*)w;    w += (size_t)(TOTN + 4) * 4;
    int* csr       = (int*)w;    w += (size_t)TOTE * 4;
    int* excl      = (int*)w;    w += (size_t)TOTN * 4;
    int* btot      = (int*)w;    w += 64 * 4;
    int* boff      = (int*)w;    w += 64 * 4;
    int* pooled    = (int*)w;    w += 320 * 4;

    hipMemsetAsync(pooled, 0, D_H * 4, stream);

    k_hist<<<dim3(NB * SLICES, 2), 256, 0, stream>>>(src1, dst1, src2, dst2, src3, dst3,
                                                     partial_in, partial_out);
    k_degscan<<<SCAN_B, 1024, 0, stream>>>(partial_in, partial_out,
                                           inv_in, inv_out, excl, btot);
    k_pack8<<<(3 * NODES * D_IN / 4 + 255) / 256, 256, 0, stream>>>(
        (const float4*)x1, (const float4*)x2, (const float4*)x3, inv_out, X8);
    k_scanB<<<1, 64, 0, stream>>>(btot, boff);
    k_offC<<<(TOTN + 256) / 256, 256, 0, stream>>>(excl, boff, partial_in, row_ptr, O);
    k_fill2<<<NB * SLICES, 256, 0, stream>>>(src1, dst1, src2, dst2, src3, dst3, O, csr);
    k_prepw<<<(D_H * 128 + 255) / 256, 256, 0, stream>>>(W1, Wt1, 128, 128);
    k_prepw<<<(D_H * 320 + 255) / 256, 256, 0, stream>>>(W2, Wt2, 304, 320);
    k_prepw<<<(D_H * 320 + 255) / 256, 256, 0, stream>>>(W3, Wt3, 304, 320);

    int ggrid = (TOTN + 127) / 128;  // 469

    // layer 1: X8(fp8*inv_out,128) -> SpMM -> P(bf16,128) -> GEMM(K=128) -> Q8
    k_spmm_f8<32, 64, 32><<<TOTN / 8, 256, 0, stream>>>(X8, P, row_ptr, csr, inv_in);
    k_gemm_mfma<0><<<ggrid, 256, 0, stream>>>((const short*)P, 128, Wt1, b1, inv_out,
                                              (unsigned char*)Q8, nullptr, TOTN, 128);
    // layer 2
    k_spmm_f8<76, 160, 64><<<TOTN / 4, 256, 0, stream>>>(Q8, P, row_ptr, csr, inv_in);
    k_gemm_mfma<0><<<ggrid, 256, 0, stream>>>((const short*)P, 320, Wt2, b2, inv_out,
                                              (unsigned char*)Q8, nullptr, TOTN, 320);
    // layer 3: GEMM fused with column max-pool (no h3 materialization)
    k_spmm_f8<76, 160, 64><<<TOTN / 4, 256, 0, stream>>>(Q8, P, row_ptr, csr, inv_in);
    k_gemm_mfma<1><<<ggrid, 256, 0, stream>>>((const short*)P, 320, Wt3, b3, nullptr,
                                              nullptr, pooled, TOTN, 320);

    k_mlp<<<1, 320, 0, stream>>>(pooled, fW1, fb1, fW2, fb2, fW3, fb3, out);
}

// Round 7
// 430.248 us; speedup vs baseline: 3.8984x; 1.0443x over previous
//
#include <hip/hip_runtime.h>
#include <hip/hip_bf16.h>
#include <math.h>

#define NODES 20000
#define EDGES 320000
#define NB 3
#define TOTN (NODES * NB)   // 60000
#define TOTE (EDGES * NB)   // 960000
#define D_IN 128
#define D_H 304
#define SCAN_B 59           // ceil(60000/1024)
#define SLICES 32
#define SLICE_E (EDGES / SLICES)   // 10000

typedef __attribute__((ext_vector_type(8))) short short8;
typedef __attribute__((ext_vector_type(4))) float f32x4;
typedef __attribute__((ext_vector_type(2))) float f32x2;

__device__ __forceinline__ unsigned short f2bf(float f) {
    unsigned u = __float_as_uint(f);
    unsigned r = (u + 0x7fffu + ((u >> 16) & 1u)) >> 16;   // RNE
    return (unsigned short)r;
}
__device__ __forceinline__ unsigned pack_bf2(float a, float b) {
    return (unsigned)f2bf(a) | ((unsigned)f2bf(b) << 16);
}
// async global->LDS, 16 B per lane; LDS dst must be wave-uniform base + lane*16
__device__ __forceinline__ void gload16(const void* g, void* l) {
    __builtin_amdgcn_global_load_lds(
        (const __attribute__((address_space(1))) unsigned*)g,
        (__attribute__((address_space(3))) unsigned*)l, 16, 0, 0);
}

// ------- pack x1|x2|x3 fp32 -> X fp8 (60000 x 128), pre-scaled by inv_out -------
__global__ void k_pack8(const float4* __restrict__ x1, const float4* __restrict__ x2,
                        const float4* __restrict__ x3, const float* __restrict__ inv_out,
                        unsigned* __restrict__ q) {
    const int per = NODES * D_IN / 4;  // out dwords per graph (32 per row)
    int i = blockIdx.x * 256 + threadIdx.x;
    if (i >= 3 * per) return;
    const float4* s; int j;
    if (i < per)          { s = x1; j = i; }
    else if (i < 2 * per) { s = x2; j = i - per; }
    else                  { s = x3; j = i - 2 * per; }
    float4 v = s[j];
    float sc = inv_out[i >> 5];   // 32 dwords per row, global node id
    int p = __builtin_amdgcn_cvt_pk_fp8_f32(v.x * sc, v.y * sc, 0, false);
    p = __builtin_amdgcn_cvt_pk_fp8_f32(v.z * sc, v.w * sc, p, true);
    q[i] = (unsigned)p;
}

// ------- per-(graph,slice) LDS histograms: no global atomics -------
__global__ __launch_bounds__(256, 1) void k_hist(
    const int* __restrict__ s1, const int* __restrict__ d1,
    const int* __restrict__ s2, const int* __restrict__ d2,
    const int* __restrict__ s3, const int* __restrict__ d3,
    int* __restrict__ partial_in, int* __restrict__ partial_out) {
    __shared__ int hist[NODES];   // 80 KB
    int g = blockIdx.x / SLICES, s = blockIdx.x % SLICES;
    bool isOut = (blockIdx.y == 1);
    const int* ep;
    if (isOut) ep = (g == 0) ? s1 : ((g == 1) ? s2 : s3);
    else       ep = (g == 0) ? d1 : ((g == 1) ? d2 : d3);
    ep += s * SLICE_E;
    for (int i = threadIdx.x; i < NODES; i += 256) hist[i] = 0;
    __syncthreads();
    for (int i = threadIdx.x; i < SLICE_E; i += 256)
        atomicAdd(&hist[ep[i]], 1);
    __syncthreads();
    int* po = (isOut ? partial_out : partial_in) + (size_t)blockIdx.x * NODES;
    for (int i = threadIdx.x; i < NODES; i += 256) po[i] = hist[i];
}

// ------- degrees from partials + inv factors + block-level scan (fused) -------
__global__ void k_degscan(const int* __restrict__ partial_in,
                          const int* __restrict__ partial_out,
                          float* __restrict__ inv_in, float* __restrict__ inv_out,
                          int* __restrict__ excl, int* __restrict__ btot) {
    __shared__ int wsum[16];
    int b = blockIdx.x, t = threadIdx.x;
    int i = b * 1024 + t;
    int lane = t & 63, wid = t >> 6;
    int v = 0;
    if (i < TOTN) {
        int g = i / NODES, ln = i - g * NODES;
        const int* pi = partial_in + (size_t)g * SLICES * NODES + ln;
        const int* po = partial_out + (size_t)g * SLICES * NODES + ln;
        int ci = 0, co = 0;
        #pragma unroll
        for (int s = 0; s < SLICES; s++) { ci += pi[s * NODES]; co += po[s * NODES]; }
        v = ci;
        inv_in[i]  = 1.0f / sqrtf((float)max(ci, 1));
        inv_out[i] = 1.0f / sqrtf((float)max(co, 1));
    }
    int sv = v;
    #pragma unroll
    for (int o = 1; o < 64; o <<= 1) {
        int u = __shfl_up(sv, o, 64);
        if (lane >= o) sv += u;
    }
    if (lane == 63) wsum[wid] = sv;
    __syncthreads();
    if (t < 16) {
        int w = wsum[t];
        #pragma unroll
        for (int o = 1; o < 16; o <<= 1) {
            int u = __shfl_up(w, o, 16);
            if (t >= o) w += u;
        }
        wsum[t] = w;
    }
    __syncthreads();
    int wbase = (wid > 0) ? wsum[wid - 1] : 0;
    if (i < TOTN) excl[i] = wbase + sv - v;
    if (t == 0) btot[b] = wsum[15];
}

__global__ void k_scanB(const int* __restrict__ btot, int* __restrict__ boff) {
    int t = threadIdx.x;  // 64
    int v = (t < SCAN_B) ? btot[t] : 0;
    int sv = v;
    #pragma unroll
    for (int o = 1; o < 64; o <<= 1) {
        int u = __shfl_up(sv, o, 64);
        if (t >= o) sv += u;
    }
    if (t < SCAN_B) boff[t] = sv - v;  // exclusive
}

// ------- row_ptr apply + per-(slice,node) CSR base offsets (fused) -------
__global__ void k_offC(const int* __restrict__ excl, const int* __restrict__ boff,
                       const int* __restrict__ partial_in,
                       int* __restrict__ row_ptr, int* __restrict__ O) {
    int n = blockIdx.x * 256 + threadIdx.x;
    if (n >= TOTN) {
        if (n == TOTN) row_ptr[TOTN] = TOTE;
        return;
    }
    if (n == 0) row_ptr[TOTN] = TOTE;
    int rp = excl[n] + boff[n >> 10];
    row_ptr[n] = rp;
    int g = n / NODES, ln = n - g * NODES;
    const int* pi = partial_in + (size_t)g * SLICES * NODES + ln;
    int* on = O + (size_t)g * SLICES * NODES + ln;
    int run = rp;
    #pragma unroll
    for (int s = 0; s < SLICES; s++) {
        on[s * NODES] = run;
        run += pi[s * NODES];
    }
}

// ------- CSR fill via LDS cursors (global-atomic-free) -------
__global__ __launch_bounds__(256, 1) void k_fill2(
    const int* __restrict__ s1, const int* __restrict__ d1,
    const int* __restrict__ s2, const int* __restrict__ d2,
    const int* __restrict__ s3, const int* __restrict__ d3,
    const int* __restrict__ O, int* __restrict__ csr) {
    __shared__ int cur[NODES];   // 80 KB
    int g = blockIdx.x / SLICES, s = blockIdx.x % SLICES;
    const int* sp = (g == 0) ? s1 : ((g == 1) ? s2 : s3);
    const int* dp = (g == 0) ? d1 : ((g == 1) ? d2 : d3);
    sp += s * SLICE_E; dp += s * SLICE_E;
    const int* on = O + (size_t)blockIdx.x * NODES;
    for (int i = threadIdx.x; i < NODES; i += 256) cur[i] = on[i];
    __syncthreads();
    int base = g * NODES;
    for (int i = threadIdx.x; i < SLICE_E; i += 256) {
        int d = dp[i];
        int sv = sp[i] + base;
        int pos = atomicAdd(&cur[d], 1);
        csr[pos] = sv;
    }
}

// ------- SpMM gather (layer 1): fp8 dword path, 32 lanes/node, unroll x8 -------
__global__ void k_spmm_l1(const unsigned* __restrict__ h, unsigned* __restrict__ agg,
                          const int* __restrict__ row_ptr, const int* __restrict__ csr,
                          const float* __restrict__ inv_in) {
    constexpr int IND = 32, OUTLD = 64, LANES = 32;
    int n = blockIdx.x * 8 + (threadIdx.x / LANES);
    int lane = threadIdx.x % LANES;
    f32x2 acc0 = (f32x2){0.f, 0.f}, acc1 = (f32x2){0.f, 0.f};
    int k0 = row_ptr[n], k1 = row_ptr[n + 1];
    int k = k0;
    for (; k + 8 <= k1; k += 8) {
        unsigned u[8];
        #pragma unroll
        for (int e = 0; e < 8; e++) u[e] = h[(size_t)csr[k + e] * IND + lane];
        #pragma unroll
        for (int e = 0; e < 8; e++) {
            acc0 += __builtin_amdgcn_cvt_pk_f32_fp8(u[e], false);
            acc1 += __builtin_amdgcn_cvt_pk_f32_fp8(u[e], true);
        }
    }
    for (; k < k1; k++) {
        unsigned u = h[(size_t)csr[k] * IND + lane];
        acc0 += __builtin_amdgcn_cvt_pk_f32_fp8(u, false);
        acc1 += __builtin_amdgcn_cvt_pk_f32_fp8(u, true);
    }
    float wi = inv_in[n];
    unsigned* ar = agg + (size_t)n * OUTLD;
    uint2 st;
    st.x = pack_bf2(acc0[0] * wi, acc0[1] * wi);
    st.y = pack_bf2(acc1[0] * wi, acc1[1] * wi);
    *(uint2*)(&ar[2 * lane]) = st;
}

// ------- SpMM gather (layers 2/3): fp8 uint2 path, 64 lanes/node, unroll x8 ----
// rows are 76 dwords = 38 uint2; lanes 0..37 active in gather
__global__ void k_spmm_big(const uint2* __restrict__ h, unsigned* __restrict__ agg,
                           const int* __restrict__ row_ptr, const int* __restrict__ csr,
                           const float* __restrict__ inv_in) {
    constexpr int UIND = 38, OUTLD = 160;
    int n = blockIdx.x * 4 + (threadIdx.x >> 6);
    int lane = threadIdx.x & 63;
    f32x2 acc[4];
    #pragma unroll
    for (int j = 0; j < 4; j++) acc[j] = (f32x2){0.f, 0.f};
    int k0 = row_ptr[n], k1 = row_ptr[n + 1];
    int k = k0;
    bool act = lane < UIND;
    for (; k + 8 <= k1; k += 8) {
        const uint2* r[8];
        #pragma unroll
        for (int e = 0; e < 8; e++) r[e] = h + (size_t)csr[k + e] * UIND;
        if (act) {
            uint2 u[8];
            #pragma unroll
            for (int e = 0; e < 8; e++) u[e] = r[e][lane];
            #pragma unroll
            for (int e = 0; e < 8; e++) {
                acc[0] += __builtin_amdgcn_cvt_pk_f32_fp8(u[e].x, false);
                acc[1] += __builtin_amdgcn_cvt_pk_f32_fp8(u[e].x, true);
                acc[2] += __builtin_amdgcn_cvt_pk_f32_fp8(u[e].y, false);
                acc[3] += __builtin_amdgcn_cvt_pk_f32_fp8(u[e].y, true);
            }
        }
    }
    for (; k < k1; k++) {
        const uint2* r0 = h + (size_t)csr[k] * UIND;
        if (act) {
            uint2 u = r0[lane];
            acc[0] += __builtin_amdgcn_cvt_pk_f32_fp8(u.x, false);
            acc[1] += __builtin_amdgcn_cvt_pk_f32_fp8(u.x, true);
            acc[2] += __builtin_amdgcn_cvt_pk_f32_fp8(u.y, false);
            acc[3] += __builtin_amdgcn_cvt_pk_f32_fp8(u.y, true);
        }
    }
    float wi = inv_in[n];
    unsigned* ar = agg + (size_t)n * OUTLD;
    if (act) {
        uint4 st;
        st.x = pack_bf2(acc[0][0] * wi, acc[0][1] * wi);
        st.y = pack_bf2(acc[1][0] * wi, acc[1][1] * wi);
        st.z = pack_bf2(acc[2][0] * wi, acc[2][1] * wi);
        st.w = pack_bf2(acc[3][0] * wi, acc[3][1] * wi);
        *(uint4*)(&ar[4 * lane]) = st;
    }
    if (lane < OUTLD - 2 * UIND) ar[2 * UIND + lane] = 0;  // zero pad 152..159
}

// ------- W prep: fp32 W[K][304] -> bf16 Wt[304][Kpad] (zero-padded K) -------
__global__ void k_prepw(const float* __restrict__ W, short* __restrict__ Wt,
                        int K, int Kpad) {
    int id = blockIdx.x * 256 + threadIdx.x;
    if (id >= D_H * Kpad) return;
    int n = id / Kpad, k = id - n * Kpad;
    short v = 0;
    if (k < K) v = (short)f2bf(W[k * D_H + n]);
    Wt[id] = v;
}

// ------- bf16 MFMA GEMM: relu(A[MxK] @ Wt^T + bias), global_load_lds staging ----
// MODE 0: store fp8 (x inv_out) to C8.  MODE 1: column max-pool -> atomicMax gpool.
// A must be readable for 128*ceil(M/128) rows (ghost rows allocated by caller).
template <int MODE>
__global__ __launch_bounds__(256, 2) void k_gemm_mfma(
    const short* __restrict__ A, int lda,
    const short* __restrict__ Wt,
    const float* __restrict__ bias,
    const float* __restrict__ inv_out,
    unsigned char* __restrict__ C8, int* __restrict__ gpool, int M, int K) {
    __shared__ short As[128 * 32];   // 8 KB, row-major stride 32
    __shared__ short Bs[304 * 32];   // 19 KB
    __shared__ int pmax[D_H];
    int tid = threadIdx.x;
    int wv = tid >> 6, lane = tid & 63;
    int quad = lane >> 4, lrow = lane & 15;
    int bm = blockIdx.x * 128;

    if (MODE == 1) {
        for (int i = tid; i < D_H; i += 256) pmax[i] = 0;
    }

    f32x4 acc[2][19];
    #pragma unroll
    for (int r = 0; r < 2; r++)
        #pragma unroll
        for (int t = 0; t < 19; t++) acc[r][t] = (f32x4){0.f, 0.f, 0.f, 0.f};

    // precompute per-thread staging coordinates (chunk = 16 B)
    int arow = tid >> 2, acol = tid & 3;           // A: 2 chunks of (row, col)
    for (int kt = 0; kt < K; kt += 32) {
        // A tile: 128 rows x 32 cols = 512 chunks
        #pragma unroll
        for (int j = 0; j < 2; j++) {
            int chunk = j * 256 + tid;
            int row = chunk >> 2, col = chunk & 3;
            gload16(A + (size_t)(bm + row) * lda + kt + col * 8, &As[chunk * 8]);
        }
        // B tile: 304 rows x 32 cols = 1216 chunks
        #pragma unroll
        for (int j = 0; j < 5; j++) {
            int chunk = j * 256 + tid;
            if (chunk < 1216) {
                int row = chunk >> 2, col = chunk & 3;
                gload16(Wt + (size_t)row * K + kt + col * 8, &Bs[chunk * 8]);
            }
        }
        __syncthreads();
        short8 a0 = *(const short8*)(&As[(wv * 32 + lrow) * 32 + quad * 8]);
        short8 a1 = *(const short8*)(&As[(wv * 32 + 16 + lrow) * 32 + quad * 8]);
        #pragma unroll
        for (int t = 0; t < 19; t++) {
            short8 b = *(const short8*)(&Bs[(t * 16 + lrow) * 32 + quad * 8]);
            acc[0][t] = __builtin_amdgcn_mfma_f32_16x16x32_bf16(a0, b, acc[0][t], 0, 0, 0);
            acc[1][t] = __builtin_amdgcn_mfma_f32_16x16x32_bf16(a1, b, acc[1][t], 0, 0, 0);
        }
        __syncthreads();
    }
    (void)arow; (void)acol;
    // epilogue: C/D layout col=lane&15, row=(lane>>4)*4+reg
    #pragma unroll
    for (int t = 0; t < 19; t++) {
        int col = t * 16 + lrow;
        float bv = bias[col];
        float m = 0.f;
        #pragma unroll
        for (int r = 0; r < 2; r++) {
            int rbase = bm + wv * 32 + r * 16 + quad * 4;
            #pragma unroll
            for (int g = 0; g < 4; g++) {
                int row = rbase + g;
                if (row < M) {
                    float v = fmaxf(acc[r][t][g] + bv, 0.f);
                    if (MODE == 0) {
                        v *= inv_out[row];   // pre-scale for next layer's gather
                        int p = __builtin_amdgcn_cvt_pk_fp8_f32(v, v, 0, false);
                        C8[(size_t)row * 304 + col] = (unsigned char)(p & 0xff);
                    } else {
                        m = fmaxf(m, v);
                    }
                }
            }
        }
        if (MODE == 1) atomicMax(&pmax[col], __float_as_int(m));
    }
    if (MODE == 1) {
        __syncthreads();
        for (int i = tid; i < D_H; i += 256)
            atomicMax(&gpool[i], pmax[i]);
    }
}

// ---------------- MLP head: 304 -> 128 -> 64 -> 1, sigmoid ----------------
__global__ void k_mlp(const int* __restrict__ pooled_i,
                      const float* __restrict__ fW1, const float* __restrict__ fb1,
                      const float* __restrict__ fW2, const float* __restrict__ fb2,
                      const float* __restrict__ fW3, const float* __restrict__ fb3,
                      float* __restrict__ out) {
    __shared__ float p[D_H];
    __shared__ float z1[128];
    __shared__ float z2[64];
    int t = threadIdx.x;  // 320
    if (t < D_H) p[t] = __int_as_float(pooled_i[t]);
    __syncthreads();
    if (t < 128) {
        float acc = fb1[t];
        for (int k = 0; k < D_H; k++) acc += p[k] * fW1[k * 128 + t];
        z1[t] = fmaxf(acc, 0.f);
    }
    __syncthreads();
    if (t < 64) {
        float acc = fb2[t];
        for (int k = 0; k < 128; k++) acc += z1[k] * fW2[k * 64 + t];
        z2[t] = fmaxf(acc, 0.f);
    }
    __syncthreads();
    if (t == 0) {
        float acc = fb3[0];
        for (int k = 0; k < 64; k++) acc += z2[k] * fW3[k];
        out[0] = 1.f / (1.f + expf(-acc));
    }
}

extern "C" void kernel_launch(void* const* d_in, const int* in_sizes, int n_in,
                              void* d_out, int out_size, void* d_ws, size_t ws_size,
                              hipStream_t stream) {
    const float* x1 = (const float*)d_in[0];
    const float* x2 = (const float*)d_in[1];
    const float* x3 = (const float*)d_in[2];
    const int* src1 = (const int*)d_in[3];
    const int* dst1 = (const int*)d_in[4];
    const int* src2 = (const int*)d_in[5];
    const int* dst2 = (const int*)d_in[6];
    const int* src3 = (const int*)d_in[7];
    const int* dst3 = (const int*)d_in[8];
    const float* W1 = (const float*)d_in[9];
    const float* b1 = (const float*)d_in[10];
    const float* W2 = (const float*)d_in[11];
    const float* b2 = (const float*)d_in[12];
    const float* W3 = (const float*)d_in[13];
    const float* b3 = (const float*)d_in[14];
    const float* fW1 = (const float*)d_in[15];
    const float* fb1 = (const float*)d_in[16];
    const float* fW2 = (const float*)d_in[17];
    const float* fb2 = (const float*)d_in[18];
    const float* fW3 = (const float*)d_in[19];
    const float* fb3 = (const float*)d_in[20];
    float* out = (float*)d_out;

    char* w = (char*)d_ws;
    unsigned* X8 = (unsigned*)w; w += (size_t)TOTN * 32 * 4;            // fp8 60000x128
    unsigned* Q8 = (unsigned*)w; w += (size_t)TOTN * 76 * 4;            // fp8 60000x304
    unsigned* P  = (unsigned*)w; w += (size_t)(TOTN + 128) * 160 * 4;   // bf16 (+ghost rows)
    short* Wt1   = (short*)w;    w += (size_t)D_H * 128 * 2;
    short* Wt2   = (short*)w;    w += (size_t)D_H * 320 * 2;
    short* Wt3   = (short*)w;    w += (size_t)D_H * 320 * 2;
    int* partial_in  = (int*)w;  w += (size_t)NB * SLICES * NODES * 4;  // 7.68 MB
    int* partial_out = (int*)w;  w += (size_t)NB * SLICES * NODES * 4;
    int* O           = (int*)w;  w += (size_t)NB * SLICES * NODES * 4;
    float* inv_out = (float*)w;  w += (size_t)TOTN * 4;
    float* inv_in  = (float*)w;  w += (size_t)TOTN * 4;
    int* row_ptr   = (int*)w;    w += (size_t)(TOTN + 4) * 4;
    int* csr       = (int*)w;    w += (size_t)TOTE * 4;
    int* excl      = (int*)w;    w += (size_t)TOTN * 4;
    int* btot      = (int*)w;    w += 64 * 4;
    int* boff      = (int*)w;    w += 64 * 4;
    int* pooled    = (int*)w;    w += 320 * 4;

    hipMemsetAsync(pooled, 0, D_H * 4, stream);

    k_hist<<<dim3(NB * SLICES, 2), 256, 0, stream>>>(src1, dst1, src2, dst2, src3, dst3,
                                                     partial_in, partial_out);
    k_degscan<<<SCAN_B, 1024, 0, stream>>>(partial_in, partial_out,
                                           inv_in, inv_out, excl, btot);
    k_pack8<<<(3 * NODES * D_IN / 4 + 255) / 256, 256, 0, stream>>>(
        (const float4*)x1, (const float4*)x2, (const float4*)x3, inv_out, X8);
    k_scanB<<<1, 64, 0, stream>>>(btot, boff);
    k_offC<<<(TOTN + 256) / 256, 256, 0, stream>>>(excl, boff, partial_in, row_ptr, O);
    k_fill2<<<NB * SLICES, 256, 0, stream>>>(src1, dst1, src2, dst2, src3, dst3, O, csr);
    k_prepw<<<(D_H * 128 + 255) / 256, 256, 0, stream>>>(W1, Wt1, 128, 128);
    k_prepw<<<(D_H * 320 + 255) / 256, 256, 0, stream>>>(W2, Wt2, 304, 320);
    k_prepw<<<(D_H * 320 + 255) / 256, 256, 0, stream>>>(W3, Wt3, 304, 320);

    int ggrid = (TOTN + 127) / 128;  // 469

    // layer 1: X8(fp8*inv_out,128) -> SpMM -> P(bf16,128) -> GEMM(K=128) -> Q8
    k_spmm_l1<<<TOTN / 8, 256, 0, stream>>>(X8, P, row_ptr, csr, inv_in);
    k_gemm_mfma<0><<<ggrid, 256, 0, stream>>>((const short*)P, 128, Wt1, b1, inv_out,
                                              (unsigned char*)Q8, nullptr, TOTN, 128);
    // layer 2
    k_spmm_big<<<TOTN / 4, 256, 0, stream>>>((const uint2*)Q8, P, row_ptr, csr, inv_in);
    k_gemm_mfma<0><<<ggrid, 256, 0, stream>>>((const short*)P, 320, Wt2, b2, inv_out,
                                              (unsigned char*)Q8, nullptr, TOTN, 320);
    // layer 3: GEMM fused with column max-pool (no h3 materialization)
    k_spmm_big<<<TOTN / 4, 256, 0, stream>>>((const uint2*)Q8, P, row_ptr, csr, inv_in);
    k_gemm_mfma<1><<<ggrid, 256, 0, stream>>>((const short*)P, 320, Wt3, b3, nullptr,
                                              nullptr, pooled, TOTN, 320);

    k_mlp<<<1, 320, 0, stream>>>(pooled, fW1, fb1, fW2, fb2, fW3, fb3, out);
}